// Round 1
// baseline (363.101 us; speedup 1.0000x reference)
//
#include <hip/hip_runtime.h>

// Shapes (fixed by the reference problem)
#define NB    8
#define NT    64
#define NI    256
#define NJ    256
#define ND    256
#define NKD   64
#define NVD   64
#define SCL   0.125f   // 1/sqrt(64) for both attention levels

// =====================================================================
// K1: Q = input_seq @ Wq + bq     (2048 rows x 64)
// grid = NB*NI blocks, 64 threads. Wq column reads are lane-coalesced.
// =====================================================================
__global__ __launch_bounds__(64) void k_proj_q(
    const float* __restrict__ x, const float* __restrict__ Wq,
    const float* __restrict__ bq, float* __restrict__ Q) {
  int row  = blockIdx.x;        // b*NI + i
  int lane = threadIdx.x;       // kd
  __shared__ __align__(16) float xs[ND];
  const float* xr = x + (size_t)row * ND;
  #pragma unroll
  for (int c = 0; c < 4; ++c) xs[lane + 64*c] = xr[lane + 64*c];
  __syncthreads();
  float acc = bq[lane];
  #pragma unroll 4
  for (int d = 0; d < ND; ++d) acc = fmaf(xs[d], Wq[d*NKD + lane], acc);
  Q[(size_t)row*NKD + lane] = acc;
}

// =====================================================================
// K2: row projection  src[rows,256] @ W[256,64] + bias
//   TR=1 (keys):   dst[bt][kd][j]   (transposed inside each (b,t) tile)
//   TR=0 (values): dst[row][kd]
// 128 rows per block, 256 threads, grid = 131072/128 = 1024.
// Thread tile: 4 rows x 8 kd. Per dd: 3 LDS b128 per 32 FMA.
// =====================================================================
template<int TR>
__global__ __launch_bounds__(256) void k_proj_kv(
    const float* __restrict__ src, const float* __restrict__ W,
    const float* __restrict__ bias, float* __restrict__ dst) {
  __shared__ __align__(16) float Wl[32*64];     // [dd][kd]      8 KB
  __shared__ __align__(16) float Xt[32*132];    // [dd][row+pad] 16.9 KB
  int tid = threadIdx.x;
  size_t row0 = (size_t)blockIdx.x * 128;
  // TR: lanes sweep rows (coalesced transposed writes); !TR: lanes sweep kd.
  int kdg = TR ? (tid>>5) : (tid&7);    // 0..7   kd = kdg*8 + c
  int rg  = TR ? (tid&31) : (tid>>3);   // 0..31  row = rg*4 + rr
  float acc[4][8] = {};
  for (int d0 = 0; d0 < ND; d0 += 32) {
    __syncthreads();
    { // stage W tile [32][64] (2048 floats, coalesced)
      const float4* Wg = (const float4*)(W + d0*NKD);
      float4* Wl4 = (float4*)Wl;
      Wl4[tid]       = Wg[tid];
      Wl4[tid + 256] = Wg[tid + 256];
    }
    { // stage X^T tile [32 d][128 rows]
      int dl = tid & 31;
      int rb = tid >> 5;
      #pragma unroll
      for (int rr2 = 0; rr2 < 16; ++rr2) {
        int r = rb + 8*rr2;
        Xt[dl*132 + r] = src[(row0 + r)*ND + d0 + dl];
      }
    }
    __syncthreads();
    #pragma unroll 4
    for (int dd = 0; dd < 32; ++dd) {
      const float4* Wr = (const float4*)(Wl + dd*64);
      float4 w0 = Wr[kdg*2];
      float4 w1 = Wr[kdg*2 + 1];
      float4 xv = *(const float4*)(Xt + dd*132 + rg*4);
      float wa[8] = {w0.x,w0.y,w0.z,w0.w,w1.x,w1.y,w1.z,w1.w};
      float xa[4] = {xv.x,xv.y,xv.z,xv.w};
      #pragma unroll
      for (int rr = 0; rr < 4; ++rr)
        #pragma unroll
        for (int c = 0; c < 8; ++c)
          acc[rr][c] = fmaf(xa[rr], wa[c], acc[rr][c]);
    }
  }
  if (TR) {
    size_t bt = row0 >> 8;
    int jb = (int)(row0 & 255) + rg*4;
    #pragma unroll
    for (int c = 0; c < 8; ++c) {
      int kd = kdg*8 + c;
      float bs = bias[kd];
      float4 o = make_float4(acc[0][c]+bs, acc[1][c]+bs, acc[2][c]+bs, acc[3][c]+bs);
      *(float4*)(dst + (bt*NKD + kd)*NJ + jb) = o;
    }
  } else {
    #pragma unroll
    for (int rr = 0; rr < 4; ++rr) {
      size_t r = row0 + rg*4 + rr;
      float4 o0 = make_float4(acc[rr][0]+bias[kdg*8+0], acc[rr][1]+bias[kdg*8+1],
                              acc[rr][2]+bias[kdg*8+2], acc[rr][3]+bias[kdg*8+3]);
      float4 o1 = make_float4(acc[rr][4]+bias[kdg*8+4], acc[rr][5]+bias[kdg*8+5],
                              acc[rr][6]+bias[kdg*8+6], acc[rr][7]+bias[kdg*8+7]);
      *(float4*)(dst + r*NKD + kdg*8)     = o0;
      *(float4*)(dst + r*NKD + kdg*8 + 4) = o1;
    }
  }
}

// =====================================================================
// K3: per-(b,t) attention. grid = 512 blocks, 256 threads (4 waves).
// 8 chunks of 32 query rows; wave w owns rows w*8..w*8+7 of each chunk.
//   S:  s[r][q] for j = lane*4+q, operands from global (Q uniform, Kt coalesced)
//   softmax in registers (shfl reductions), raw row max -> Sc
//   PV: j split across 8-lane groups, 8i x 8k register partials, shfl reduce
// No __syncthreads in the main loop (all LDS sharing is intra-wave).
// =====================================================================
__global__ __launch_bounds__(256) void k_attn(
    const float* __restrict__ Q,    // [b, i, kd]
    const float* __restrict__ Kt,   // [bt, kd, j]
    const float* __restrict__ V,    // [bt, j, vd]
    float* __restrict__ R,          // [bt, i, vd]
    float* __restrict__ Sc) {       // [bt, i]
  __shared__ __align__(16) float Pl[32*256];   // P rows for current chunk, 32 KB
  int tid  = threadIdx.x;
  int w    = tid >> 6;       // wave 0..3
  int lane = tid & 63;
  int bt   = blockIdx.x;
  int b    = bt >> 6;
  const float* Ktb = Kt + (size_t)bt*NKD*NJ;
  const float* Vb  = V  + (size_t)bt*NJ*NVD;
  int kg = lane & 7;         // k-group: k = kg*8 + c
  int jg = lane >> 3;        // j4-subset selector for PV

  for (int ic = 0; ic < 8; ++ic) {
    int i0 = ic*32;
    size_t qbase = ((size_t)b*NI + i0 + w*8)*NKD;
    // ---------------- S = Q @ Kt  (rows w*8..w*8+7, j = lane*4+q) ---------
    float s[8][4];
    #pragma unroll
    for (int r = 0; r < 8; ++r) { s[r][0]=0.f; s[r][1]=0.f; s[r][2]=0.f; s[r][3]=0.f; }
    for (int kq = 0; kq < 16; ++kq) {
      float kt[4][4];
      #pragma unroll
      for (int kk = 0; kk < 4; ++kk) {
        float4 t = *(const float4*)(Ktb + (size_t)(kq*4+kk)*NJ + lane*4);
        kt[kk][0]=t.x; kt[kk][1]=t.y; kt[kk][2]=t.z; kt[kk][3]=t.w;
      }
      #pragma unroll
      for (int r = 0; r < 8; ++r) {
        float4 qv = *(const float4*)(Q + qbase + (size_t)r*NKD + kq*4);
        float qa[4] = {qv.x, qv.y, qv.z, qv.w};
        #pragma unroll
        for (int kk = 0; kk < 4; ++kk)
          #pragma unroll
          for (int q = 0; q < 4; ++q)
            s[r][q] = fmaf(qa[kk], kt[kk][q], s[r][q]);
      }
    }
    // ---------------- softmax over j (in registers) -----------------------
    float linv[8];
    #pragma unroll
    for (int r = 0; r < 8; ++r) {
      float mx = fmaxf(fmaxf(s[r][0], s[r][1]), fmaxf(s[r][2], s[r][3]));
      #pragma unroll
      for (int off = 32; off; off >>= 1) mx = fmaxf(mx, __shfl_xor(mx, off));
      if (lane == 0) Sc[(size_t)bt*NI + i0 + w*8 + r] = mx;   // raw max
      float p0 = __expf((s[r][0]-mx)*SCL);
      float p1 = __expf((s[r][1]-mx)*SCL);
      float p2 = __expf((s[r][2]-mx)*SCL);
      float p3 = __expf((s[r][3]-mx)*SCL);
      float l = p0+p1+p2+p3;
      #pragma unroll
      for (int off = 32; off; off >>= 1) l += __shfl_xor(l, off);
      linv[r] = 1.0f / l;
      *(float4*)(Pl + (w*8+r)*256 + lane*4) = make_float4(p0,p1,p2,p3);
    }
    // ---------------- PV: R[i][k] = sum_j P[i][j] V[j][k] ------------------
    float rv[8][8];
    #pragma unroll
    for (int r = 0; r < 8; ++r)
      #pragma unroll
      for (int c = 0; c < 8; ++c) rv[r][c] = 0.f;
    for (int n = 0; n < 8; ++n) {
      int j4 = jg + n*8;              // this lane group's j-quad
      float pv[8][4];
      #pragma unroll
      for (int r = 0; r < 8; ++r) {
        float4 t = *(const float4*)(Pl + (w*8+r)*256 + j4*4);
        pv[r][0]=t.x; pv[r][1]=t.y; pv[r][2]=t.z; pv[r][3]=t.w;
      }
      #pragma unroll
      for (int jj = 0; jj < 4; ++jj) {
        const float* vrow = Vb + (size_t)(j4*4+jj)*NVD + kg*8;
        float4 va  = *(const float4*)vrow;
        float4 vb4 = *(const float4*)(vrow + 4);
        float vv[8] = {va.x,va.y,va.z,va.w,vb4.x,vb4.y,vb4.z,vb4.w};
        #pragma unroll
        for (int r = 0; r < 8; ++r)
          #pragma unroll
          for (int c = 0; c < 8; ++c)
            rv[r][c] = fmaf(pv[r][jj], vv[c], rv[r][c]);
      }
    }
    // cross-lane-group reduction over jg (bits 3..5 of lane)
    #pragma unroll
    for (int r = 0; r < 8; ++r)
      #pragma unroll
      for (int c = 0; c < 8; ++c) {
        float v = rv[r][c];
        v += __shfl_xor(v, 8);
        v += __shfl_xor(v, 16);
        v += __shfl_xor(v, 32);
        rv[r][c] = v;
      }
    if (jg == 0) {
      #pragma unroll
      for (int r = 0; r < 8; ++r) {
        float* dstp = R + ((size_t)bt*NI + i0 + w*8 + r)*NVD + kg*8;
        float4 o0 = make_float4(rv[r][0]*linv[r], rv[r][1]*linv[r],
                                rv[r][2]*linv[r], rv[r][3]*linv[r]);
        float4 o1 = make_float4(rv[r][4]*linv[r], rv[r][5]*linv[r],
                                rv[r][6]*linv[r], rv[r][7]*linv[r]);
        *(float4*)dstp     = o0;
        *(float4*)(dstp+4) = o1;
      }
    }
  }
}

// =====================================================================
// K4: level-2 attention over t.  grid = NB*NI blocks, 64 threads.
// lane doubles as t (softmax) and k (output column).
// =====================================================================
__global__ __launch_bounds__(64) void k_level2(
    const float* __restrict__ Sc,   // [b, t, i]
    const float* __restrict__ R,    // [b, t, i, vd]
    float* __restrict__ out) {      // [b, i, vd]
  int bi = blockIdx.x;
  int b = bi >> 8, i = bi & 255;
  int lane = threadIdx.x;
  float sc = Sc[((size_t)b*NT + lane)*NI + i];
  float mx = sc;
  #pragma unroll
  for (int off = 32; off; off >>= 1) mx = fmaxf(mx, __shfl_xor(mx, off));
  float e = __expf((sc - mx)*SCL);
  float sum = e;
  #pragma unroll
  for (int off = 32; off; off >>= 1) sum += __shfl_xor(sum, off);
  float wn = e / sum;                 // this lane's weight for t = lane
  float acc = 0.f;
  for (int t = 0; t < NT; ++t) {
    float wt = __shfl(wn, t);
    acc = fmaf(wt, R[(((size_t)b*NT + t)*NI + i)*NVD + lane], acc);
  }
  out[((size_t)b*NI + i)*NVD + lane] = acc;
}

// =====================================================================
extern "C" void kernel_launch(void* const* d_in, const int* in_sizes, int n_in,
                              void* d_out, int out_size, void* d_ws, size_t ws_size,
                              hipStream_t stream) {
  const float* x   = (const float*)d_in[0];  // [8,256,256]
  const float* mx  = (const float*)d_in[1];  // [8,64,256,256]
  const float* my  = (const float*)d_in[2];  // [8,64,256,256]
  const float* Wq  = (const float*)d_in[3];  // [256,64]
  const float* bq  = (const float*)d_in[4];  // [64]
  const float* Wk  = (const float*)d_in[5];
  const float* bk  = (const float*)d_in[6];
  const float* Wv  = (const float*)d_in[7];
  const float* bv  = (const float*)d_in[8];
  float* out = (float*)d_out;

  // workspace layout (floats): needs ~101.7 MB
  float* ws  = (float*)d_ws;
  float* Qw  = ws;                        // 131072
  float* Ktw = Qw  + 131072;              // 8388608  [bt][kd][j]
  float* Vw  = Ktw + 8388608;             // 8388608  [bt][j][kd]
  float* Rw  = Vw  + 8388608;             // 8388608  [bt][i][kd]
  float* Scw = Rw  + 8388608;             // 131072   [bt][i]

  hipLaunchKernelGGL(k_proj_q, dim3(NB*NI), dim3(64), 0, stream, x, Wq, bq, Qw);
  hipLaunchKernelGGL(HIP_KERNEL_NAME(k_proj_kv<1>), dim3(1024), dim3(256), 0, stream,
                     mx, Wk, bk, Ktw);
  hipLaunchKernelGGL(HIP_KERNEL_NAME(k_proj_kv<0>), dim3(1024), dim3(256), 0, stream,
                     my, Wv, bv, Vw);
  hipLaunchKernelGGL(k_attn, dim3(NB*NT), dim3(256), 0, stream, Qw, Ktw, Vw, Rw, Scw);
  hipLaunchKernelGGL(k_level2, dim3(NB*NI), dim3(64), 0, stream, Scw, Rw, out);
}

// Round 2
// 212.543 us; speedup vs baseline: 1.7084x; 1.7084x over previous
//
#include <hip/hip_runtime.h>

// Shapes (fixed)
#define NB 8
#define NT 64
#define NI 256
#define NJ 256
#define ND 256
#define NKD 64
#define NVD 64
#define SCL 0.125f   // 1/sqrt(64), both attention levels

typedef __attribute__((ext_vector_type(4))) float f32x4;
typedef __attribute__((ext_vector_type(8))) short bf16x8;  // 8 bf16 = 4 VGPR (MFMA A/B frag)
typedef __attribute__((ext_vector_type(4))) short bf16x4;  // 4 bf16 = 8 B packed store

// D[16 M][16 N] = A[16 M][32 K] * B[32 K][16 N] + C
// A frag: lane l holds A[l%16][8*(l/16)+e], e=0..7 ; B frag: B[8*(l/16)+e][l%16]
// C/D:    lane l holds D[4*(l/16)+r][l%16], r=0..3   (measured layout, m89/m91)
#define MFMA16(A, B, C) __builtin_amdgcn_mfma_f32_16x16x32_bf16((A), (B), (C), 0, 0, 0)

__device__ __forceinline__ unsigned short bf16_rne(float x) {
  unsigned u = __builtin_bit_cast(unsigned, x);
  u += 0x7fffu + ((u >> 16) & 1u);
  return (unsigned short)(u >> 16);
}
__device__ __forceinline__ float bf16_f32(unsigned short h) {
  return __builtin_bit_cast(float, (unsigned)h << 16);
}
// split fp32 -> hi + lo bf16 (hi = RNE(x), lo = RNE(x - hi)); hi+lo = x to ~2^-18 rel
__device__ __forceinline__ void split8(const float* __restrict__ x, bf16x8& hi, bf16x8& lo) {
  #pragma unroll
  for (int e = 0; e < 8; ++e) {
    unsigned short h = bf16_rne(x[e]);
    hi[e] = (short)h;
    lo[e] = (short)bf16_rne(x[e] - bf16_f32(h));
  }
}

// =====================================================================
// K0: pre-transpose + split weights:  W[256][64] -> Wt_hi/lo[64][256]
// =====================================================================
__global__ __launch_bounds__(256) void k_prep_wt(
    const float* __restrict__ Wk, const float* __restrict__ Wv,
    unsigned short* __restrict__ Wkth, unsigned short* __restrict__ Wktl,
    unsigned short* __restrict__ Wvth, unsigned short* __restrict__ Wvtl) {
  int t = blockIdx.x * 256 + threadIdx.x;   // 0..16383
  int d = t >> 6, kd = t & 63;
  float x = Wk[t];
  unsigned short h = bf16_rne(x);
  Wkth[kd * 256 + d] = h;
  Wktl[kd * 256 + d] = bf16_rne(x - bf16_f32(h));
  x = Wv[t];
  h = bf16_rne(x);
  Wvth[kd * 256 + d] = h;
  Wvtl[kd * 256 + d] = bf16_rne(x - bf16_f32(h));
}

// =====================================================================
// K1: Q = input_seq @ Wq + bq  (fp32 compute), output split bf16 hi/lo
// =====================================================================
__global__ __launch_bounds__(64) void k_proj_q(
    const float* __restrict__ x, const float* __restrict__ Wq,
    const float* __restrict__ bq,
    unsigned short* __restrict__ Qh, unsigned short* __restrict__ Ql) {
  int row = blockIdx.x, lane = threadIdx.x;
  __shared__ __align__(16) float xs[ND];
  const float* xr = x + (size_t)row * ND;
  #pragma unroll
  for (int cc = 0; cc < 4; ++cc) xs[lane + 64 * cc] = xr[lane + 64 * cc];
  __syncthreads();
  float acc = bq[lane];
  #pragma unroll 4
  for (int d = 0; d < ND; ++d) acc = fmaf(xs[d], Wq[d * NKD + lane], acc);
  unsigned short h = bf16_rne(acc);
  Qh[(size_t)row * NKD + lane] = h;
  Ql[(size_t)row * NKD + lane] = bf16_rne(acc - bf16_f32(h));
}

// =====================================================================
// K2a: K-projection, swapped orientation: D[kd][j] = Wt * X^T (+bk)
// out: Kh/Kl[bt*256 + j][64] bf16 planes. 256 thr (4 waves), 128 rows/blk.
// wave tile: 64 kd (4 mf) x 32 j (2 nj). 3-term split MFMA, no LDS.
// =====================================================================
__global__ __launch_bounds__(256) void k_proj_k(
    const float* __restrict__ X,
    const unsigned short* __restrict__ Wth, const unsigned short* __restrict__ Wtl,
    const float* __restrict__ bias,
    unsigned short* __restrict__ Kh, unsigned short* __restrict__ Kl) {
  int tid = threadIdx.x;
  int w = tid >> 6, lane = tid & 63, c = lane & 15, g = lane >> 4;
  size_t row0 = (size_t)blockIdx.x * 128 + w * 32;
  f32x4 acc[4][2];
  #pragma unroll
  for (int mf = 0; mf < 4; ++mf)
    #pragma unroll
    for (int nj = 0; nj < 2; ++nj) acc[mf][nj] = (f32x4)0.f;

  #pragma unroll 2
  for (int ks = 0; ks < 8; ++ks) {
    int k0 = ks * 32;
    bf16x8 awh[4], awl[4];
    #pragma unroll
    for (int mf = 0; mf < 4; ++mf) {   // A: Wt[kd = mf*16+c][k0+8g..+8]
      size_t off = (size_t)(mf * 16 + c) * ND + k0 + g * 8;
      awh[mf] = *(const bf16x8*)(Wth + off);
      awl[mf] = *(const bf16x8*)(Wtl + off);
    }
    bf16x8 bxh[2], bxl[2];
    #pragma unroll
    for (int nj = 0; nj < 2; ++nj) {   // B: X[j = row0+nj*16+c][k0+8g..+8]
      float xv[8];
      const float* xp = X + (row0 + nj * 16 + c) * ND + k0 + g * 8;
      *(float4*)&xv[0] = *(const float4*)xp;
      *(float4*)&xv[4] = *(const float4*)(xp + 4);
      split8(xv, bxh[nj], bxl[nj]);
    }
    #pragma unroll
    for (int mf = 0; mf < 4; ++mf)
      #pragma unroll
      for (int nj = 0; nj < 2; ++nj) {
        acc[mf][nj] = MFMA16(awh[mf], bxh[nj], acc[mf][nj]);
        acc[mf][nj] = MFMA16(awl[mf], bxh[nj], acc[mf][nj]);
        acc[mf][nj] = MFMA16(awh[mf], bxl[nj], acc[mf][nj]);
      }
  }
  float bb[4][4];
  #pragma unroll
  for (int mf = 0; mf < 4; ++mf)
    #pragma unroll
    for (int r = 0; r < 4; ++r) bb[mf][r] = bias[mf * 16 + g * 4 + r];
  #pragma unroll
  for (int nj = 0; nj < 2; ++nj) {
    size_t jrow = row0 + nj * 16 + c;
    #pragma unroll
    for (int mf = 0; mf < 4; ++mf) {   // element (kd = mf*16+4g+r, j)
      bf16x4 ph, plo;
      #pragma unroll
      for (int r = 0; r < 4; ++r) {
        float v = acc[mf][nj][r] + bb[mf][r];
        unsigned short h = bf16_rne(v);
        ph[r] = (short)h;
        plo[r] = (short)bf16_rne(v - bf16_f32(h));
      }
      *(bf16x4*)(Kh + jrow * NKD + mf * 16 + g * 4) = ph;
      *(bf16x4*)(Kl + jrow * NKD + mf * 16 + g * 4) = plo;
    }
  }
}

// =====================================================================
// K2b: V-projection, normal orientation: D[j][vd] = X * Wt^T-frags (+bv)
// out TRANSPOSED: Vth/Vtl[bt][vd][j]. 256 thr, 128 rows/blk.
// wave tile: 32 j (2 mf) x 64 vd (4 nf).
// =====================================================================
__global__ __launch_bounds__(256) void k_proj_v(
    const float* __restrict__ X,
    const unsigned short* __restrict__ Wth, const unsigned short* __restrict__ Wtl,
    const float* __restrict__ bias,
    unsigned short* __restrict__ Vth, unsigned short* __restrict__ Vtl) {
  int tid = threadIdx.x;
  int w = tid >> 6, lane = tid & 63, c = lane & 15, g = lane >> 4;
  size_t row0 = (size_t)blockIdx.x * 128 + w * 32;
  f32x4 acc[2][4];
  #pragma unroll
  for (int mf = 0; mf < 2; ++mf)
    #pragma unroll
    for (int nf = 0; nf < 4; ++nf) acc[mf][nf] = (f32x4)0.f;

  #pragma unroll 2
  for (int ks = 0; ks < 8; ++ks) {
    int k0 = ks * 32;
    bf16x8 axh[2], axl[2];
    #pragma unroll
    for (int mf = 0; mf < 2; ++mf) {   // A: X[j = row0+mf*16+c][k0+8g..+8]
      float xv[8];
      const float* xp = X + (row0 + mf * 16 + c) * ND + k0 + g * 8;
      *(float4*)&xv[0] = *(const float4*)xp;
      *(float4*)&xv[4] = *(const float4*)(xp + 4);
      split8(xv, axh[mf], axl[mf]);
    }
    bf16x8 bwh[4], bwl[4];
    #pragma unroll
    for (int nf = 0; nf < 4; ++nf) {   // B: Wt[vd = nf*16+c][k0+8g..+8]
      size_t off = (size_t)(nf * 16 + c) * ND + k0 + g * 8;
      bwh[nf] = *(const bf16x8*)(Wth + off);
      bwl[nf] = *(const bf16x8*)(Wtl + off);
    }
    #pragma unroll
    for (int mf = 0; mf < 2; ++mf)
      #pragma unroll
      for (int nf = 0; nf < 4; ++nf) {
        acc[mf][nf] = MFMA16(axh[mf], bwh[nf], acc[mf][nf]);
        acc[mf][nf] = MFMA16(axl[mf], bwh[nf], acc[mf][nf]);
        acc[mf][nf] = MFMA16(axh[mf], bwl[nf], acc[mf][nf]);
      }
  }
  size_t bt = row0 >> 8;               // block never straddles a bt (128 | 256)
  int jb0 = (int)(row0 & 255);
  #pragma unroll
  for (int nf = 0; nf < 4; ++nf) {
    int vd = nf * 16 + c;
    float bs = bias[vd];
    #pragma unroll
    for (int mf = 0; mf < 2; ++mf) {   // element (j = jb0+mf*16+4g+r, vd)
      bf16x4 ph, plo;
      #pragma unroll
      for (int r = 0; r < 4; ++r) {
        float v = acc[mf][nf][r] + bs;
        unsigned short h = bf16_rne(v);
        ph[r] = (short)h;
        plo[r] = (short)bf16_rne(v - bf16_f32(h));
      }
      size_t off = ((size_t)bt * NKD + vd) * NJ + jb0 + mf * 16 + g * 4;
      *(bf16x4*)(Vth + off) = ph;
      *(bf16x4*)(Vtl + off) = plo;
    }
  }
}

// =====================================================================
// K3: attention per (b,t). 512 thr (8 waves), grid 512. LDS 128 KB:
//   plane0 Kh[256 j][64 kd], plane1 Kl, plane2 Vth[64 vd][256 j], plane3 Vtl
//   (bf16, 16B-block XOR swizzle: K: blk^ (j&7); V: blk ^ (vd&7))
// Wave w owns i-columns w*32 .. +32 (two ic halves of 16).
// S^T = K*Q^T (3-term) -> lane-local softmax -> P^T via LDS bounce
// (dead K region, per-wave 8 KB) -> R^T = Vt*P^T (2-term) -> R bf16.
// =====================================================================
__global__ __launch_bounds__(512) void k_attn(
    const unsigned short* __restrict__ Qh, const unsigned short* __restrict__ Ql,
    const unsigned short* __restrict__ Kh, const unsigned short* __restrict__ Kl,
    const unsigned short* __restrict__ Vth, const unsigned short* __restrict__ Vtl,
    unsigned short* __restrict__ R,      // [bt][256 i][64 vd] bf16
    float* __restrict__ Sc) {            // [bt][256 i] raw row max
  __shared__ uint4 smem4[8192];          // 128 KB
  char* smemb = (char*)smem4;
  int tid = threadIdx.x;
  int bt = blockIdx.x, b = bt >> 6;
  int w = tid >> 6, lane = tid & 63, c = lane & 15, g = lane >> 4;

  // ---- stage the 4 planes (reg-staged, swizzled ds_write) ----
  #pragma unroll
  for (int pl = 0; pl < 4; ++pl) {
    const unsigned short* src =
        (pl == 0) ? Kh + (size_t)bt * 16384 :
        (pl == 1) ? Kl + (size_t)bt * 16384 :
        (pl == 2) ? Vth + (size_t)bt * 16384 :
                    Vtl + (size_t)bt * 16384;
    #pragma unroll
    for (int it = 0; it < 4; ++it) {
      int qq = tid + it * 512;           // 16B chunk id within plane (0..2047)
      uint4 v = *(const uint4*)((const char*)src + (size_t)qq * 16);
      int dst;
      if (pl < 2) { int j = qq >> 3;  int pb = qq & 7;  dst = pl * 32768 + j * 128 + ((pb ^ (j & 7)) << 4); }
      else        { int vd = qq >> 5; int pb = qq & 31; dst = pl * 32768 + vd * 512 + ((pb ^ (vd & 7)) << 4); }
      *(uint4*)(smemb + dst) = v;
    }
  }
  // Q B-frags from global (L2-hot)
  int i0 = w * 32;
  bf16x8 qbh[2][2], qbl[2][2];
  #pragma unroll
  for (int ks = 0; ks < 2; ++ks)
    #pragma unroll
    for (int ic = 0; ic < 2; ++ic) {
      size_t qoff = ((size_t)(b * NI + i0 + ic * 16 + c)) * NKD + ks * 32 + g * 8;
      qbh[ks][ic] = *(const bf16x8*)(Qh + qoff);
      qbl[ks][ic] = *(const bf16x8*)(Ql + qoff);
    }
  __syncthreads();

  // ---- S^T phase: sa[jf][ic] holds S^T[j = 16jf+4g+r][i = i0+16ic+c] ----
  f32x4 sa[16][2];
  #pragma unroll
  for (int jf = 0; jf < 16; ++jf) { sa[jf][0] = (f32x4)0.f; sa[jf][1] = (f32x4)0.f; }
  #pragma unroll
  for (int jf = 0; jf < 16; ++jf) {
    #pragma unroll
    for (int ks = 0; ks < 2; ++ks) {
      int j = jf * 16 + c;
      int ba = j * 128 + (((ks * 4 + g) ^ (j & 7)) << 4);
      bf16x8 kh = *(const bf16x8*)(smemb + ba);
      bf16x8 kl = *(const bf16x8*)(smemb + 32768 + ba);
      #pragma unroll
      for (int ic = 0; ic < 2; ++ic) {
        sa[jf][ic] = MFMA16(kh, qbh[ks][ic], sa[jf][ic]);
        sa[jf][ic] = MFMA16(kl, qbh[ks][ic], sa[jf][ic]);
        sa[jf][ic] = MFMA16(kh, qbl[ks][ic], sa[jf][ic]);
      }
    }
  }
  __syncthreads();   // K region dead; reuse as per-wave P^T buffers

  char* pbase = smemb + w * 8192;      // P^T[16 i-local][256 j] bf16, swizzled

  #pragma unroll
  for (int ic = 0; ic < 2; ++ic) {
    // softmax over j for column i = i0 + 16ic + c (lane-local + 2 shfl)
    float mx = sa[0][ic][0];
    #pragma unroll
    for (int jf = 0; jf < 16; ++jf)
      #pragma unroll
      for (int r = 0; r < 4; ++r) mx = fmaxf(mx, sa[jf][ic][r]);
    mx = fmaxf(mx, __shfl_xor(mx, 16));
    mx = fmaxf(mx, __shfl_xor(mx, 32));
    if (g == 0) Sc[(size_t)bt * NI + i0 + ic * 16 + c] = mx;  // raw max
    float sum = 0.f;
    #pragma unroll
    for (int jf = 0; jf < 16; ++jf)
      #pragma unroll
      for (int r = 0; r < 4; ++r) {
        float p = __expf((sa[jf][ic][r] - mx) * SCL);
        sa[jf][ic][r] = p;
        sum += p;
      }
    sum += __shfl_xor(sum, 16);
    sum += __shfl_xor(sum, 32);
    float linv = 1.0f / sum;

    // write P^T: row c, j = 16jf + 4g + r (pack 4), swizzled 16B blocks
    #pragma unroll
    for (int jf = 0; jf < 16; ++jf) {
      int byteoff = jf * 32 + g * 8;
      int sw = (((byteoff >> 4) ^ (c & 7)) << 4) | (byteoff & 15);
      bf16x4 pk;
      #pragma unroll
      for (int r = 0; r < 4; ++r) pk[r] = (short)bf16_rne(sa[jf][ic][r]);
      *(bf16x4*)(pbase + c * 512 + sw) = pk;
    }

    // PV: R^T[vd][i] = sum_j Vt[vd][j] * P^T[j][i]  (2-term V split)
    f32x4 racc[4];
    #pragma unroll
    for (int vf = 0; vf < 4; ++vf) racc[vf] = (f32x4)0.f;
    for (int js = 0; js < 8; ++js) {
      int pblk = (js * 4 + g) ^ (c & 7);
      bf16x8 pb = *(const bf16x8*)(pbase + c * 512 + (pblk << 4));
      #pragma unroll
      for (int vf = 0; vf < 4; ++vf) {
        int vd = vf * 16 + c;
        int vba = 2 * 32768 + vd * 512 + (((js * 4 + g) ^ (vd & 7)) << 4);
        bf16x8 vh = *(const bf16x8*)(smemb + vba);
        bf16x8 vl = *(const bf16x8*)(smemb + vba + 32768);
        racc[vf] = MFMA16(vh, pb, racc[vf]);
        racc[vf] = MFMA16(vl, pb, racc[vf]);
      }
    }
    // write R[bt][i][vd] bf16, normalized; element (vd = vf*16+4g+r, i)
    int i = i0 + ic * 16 + c;
    #pragma unroll
    for (int vf = 0; vf < 4; ++vf) {
      bf16x4 rk;
      #pragma unroll
      for (int r = 0; r < 4; ++r) rk[r] = (short)bf16_rne(racc[vf][r] * linv);
      *(bf16x4*)(R + ((size_t)bt * NI + i) * NKD + vf * 16 + g * 4) = rk;
    }
  }
}

// =====================================================================
// K4: level-2 attention over t. grid = NB*NI, 64 thr. lane = t then vd.
// =====================================================================
__global__ __launch_bounds__(64) void k_level2(
    const float* __restrict__ Sc,        // [bt][256]
    const unsigned short* __restrict__ R, // [bt][256][64] bf16
    float* __restrict__ out) {            // [b][256][64] f32
  int bi = blockIdx.x;
  int b = bi >> 8, i = bi & 255;
  int lane = threadIdx.x;
  float sc = Sc[((size_t)b * NT + lane) * NI + i];
  float mx = sc;
  #pragma unroll
  for (int off = 32; off; off >>= 1) mx = fmaxf(mx, __shfl_xor(mx, off));
  float e = __expf((sc - mx) * SCL);
  float sum = e;
  #pragma unroll
  for (int off = 32; off; off >>= 1) sum += __shfl_xor(sum, off);
  float wn = e / sum;
  float acc = 0.f;
  for (int t = 0; t < NT; ++t) {
    float wt = __shfl(wn, t);
    acc = fmaf(wt, bf16_f32(R[(((size_t)b * NT + t) * NI + i) * NKD + lane]), acc);
  }
  out[((size_t)b * NI + i) * NVD + lane] = acc;
}

// =====================================================================
extern "C" void kernel_launch(void* const* d_in, const int* in_sizes, int n_in,
                              void* d_out, int out_size, void* d_ws, size_t ws_size,
                              hipStream_t stream) {
  const float* x   = (const float*)d_in[0];
  const float* mx  = (const float*)d_in[1];
  const float* my  = (const float*)d_in[2];
  const float* Wq  = (const float*)d_in[3];
  const float* bq  = (const float*)d_in[4];
  const float* Wk  = (const float*)d_in[5];
  const float* bk  = (const float*)d_in[6];
  const float* Wv  = (const float*)d_in[7];
  const float* bv  = (const float*)d_in[8];
  float* out = (float*)d_out;

  // workspace carve (~85.3 MB)
  char* p = (char*)d_ws;
  auto alloc = [&](size_t bytes) { char* r = p; p += (bytes + 255) & ~(size_t)255; return r; };
  unsigned short* Qh   = (unsigned short*)alloc(2048 * 64 * 2);
  unsigned short* Ql   = (unsigned short*)alloc(2048 * 64 * 2);
  unsigned short* Khw  = (unsigned short*)alloc((size_t)131072 * 64 * 2);
  unsigned short* Klw  = (unsigned short*)alloc((size_t)131072 * 64 * 2);
  unsigned short* Vthw = (unsigned short*)alloc((size_t)131072 * 64 * 2);
  unsigned short* Vtlw = (unsigned short*)alloc((size_t)131072 * 64 * 2);
  unsigned short* Rw   = (unsigned short*)alloc((size_t)131072 * 64 * 2);
  float*          Scw  = (float*)alloc((size_t)131072 * 4);
  unsigned short* Wkth = (unsigned short*)alloc(64 * 256 * 2);
  unsigned short* Wktl = (unsigned short*)alloc(64 * 256 * 2);
  unsigned short* Wvth = (unsigned short*)alloc(64 * 256 * 2);
  unsigned short* Wvtl = (unsigned short*)alloc(64 * 256 * 2);

  hipLaunchKernelGGL(k_prep_wt, dim3(64), dim3(256), 0, stream,
                     Wk, Wv, Wkth, Wktl, Wvth, Wvtl);
  hipLaunchKernelGGL(k_proj_q, dim3(NB * NI), dim3(64), 0, stream, x, Wq, bq, Qh, Ql);
  hipLaunchKernelGGL(k_proj_k, dim3(1024), dim3(256), 0, stream,
                     mx, Wkth, Wktl, bk, Khw, Klw);
  hipLaunchKernelGGL(k_proj_v, dim3(1024), dim3(256), 0, stream,
                     my, Wvth, Wvtl, bv, Vthw, Vtlw);
  hipLaunchKernelGGL(k_attn, dim3(NB * NT), dim3(512), 0, stream,
                     Qh, Ql, Khw, Klw, Vthw, Vtlw, Rw, Scw);
  hipLaunchKernelGGL(k_level2, dim3(NB * NI), dim3(64), 0, stream, Scw, Rw, out);
}

// Round 4
// 208.109 us; speedup vs baseline: 1.7448x; 1.0213x over previous
//
#include <hip/hip_runtime.h>
#include <hip/hip_bf16.h>

// Shapes (fixed)
#define NB 8
#define NT 64
#define NI 256
#define NJ 256
#define ND 256
#define NKD 64
#define NVD 64
#define SCL 0.125f   // 1/sqrt(64), both attention levels

typedef __attribute__((ext_vector_type(4))) float f32x4;
typedef __attribute__((ext_vector_type(8))) short bf16x8;  // 8 bf16 = 4 VGPR (MFMA A/B frag)
typedef __attribute__((ext_vector_type(4))) short bf16x4;  // 4 bf16 = 8 B packed store
typedef __attribute__((ext_vector_type(4))) unsigned int uint32x4;

// D[16 M][16 N] = A[16 M][32 K] * B[32 K][16 N] + C
// A frag: lane l holds A[l%16][8*(l/16)+e] ; B frag: B[8*(l/16)+e][l%16]
// C/D:    lane l holds D[4*(l/16)+r][l%16]
#define MFMA16(A, B, C) __builtin_amdgcn_mfma_f32_16x16x32_bf16((A), (B), (C), 0, 0, 0)

__device__ __forceinline__ unsigned short f2bf(float x) {   // RNE
  return __builtin_bit_cast(unsigned short, __float2bfloat16(x));
}
__device__ __forceinline__ float bf2f(unsigned short h) {
  return __builtin_bit_cast(float, (unsigned)h << 16);
}
// split fp32 -> hi + lo bf16; hi+lo = x to ~2^-18 rel
__device__ __forceinline__ void split8(const float* __restrict__ x, bf16x8& hi, bf16x8& lo) {
  #pragma unroll
  for (int e = 0; e < 8; ++e) {
    unsigned short h = f2bf(x[e]);
    hi[e] = (short)h;
    lo[e] = (short)f2bf(x[e] - bf2f(h));
  }
}

// =====================================================================
// K0: pre-transpose + split weights:  W[256][64] -> Wt_hi/lo[64][256]
// =====================================================================
__global__ __launch_bounds__(256) void k_prep_wt(
    const float* __restrict__ Wk, const float* __restrict__ Wv,
    unsigned short* __restrict__ Wkth, unsigned short* __restrict__ Wktl,
    unsigned short* __restrict__ Wvth, unsigned short* __restrict__ Wvtl) {
  int t = blockIdx.x * 256 + threadIdx.x;   // 0..16383
  int d = t >> 6, kd = t & 63;
  float x = Wk[t];
  unsigned short h = f2bf(x);
  Wkth[kd * 256 + d] = h;
  Wktl[kd * 256 + d] = f2bf(x - bf2f(h));
  x = Wv[t];
  h = f2bf(x);
  Wvth[kd * 256 + d] = h;
  Wvtl[kd * 256 + d] = f2bf(x - bf2f(h));
}

// =====================================================================
// K1: Q = input_seq @ Wq + bq  (fp32 compute), output split bf16 hi/lo
// =====================================================================
__global__ __launch_bounds__(64) void k_proj_q(
    const float* __restrict__ x, const float* __restrict__ Wq,
    const float* __restrict__ bq,
    unsigned short* __restrict__ Qh, unsigned short* __restrict__ Ql) {
  int row = blockIdx.x, lane = threadIdx.x;
  __shared__ __align__(16) float xs[ND];
  const float* xr = x + (size_t)row * ND;
  #pragma unroll
  for (int cc = 0; cc < 4; ++cc) xs[lane + 64 * cc] = xr[lane + 64 * cc];
  __syncthreads();
  float acc = bq[lane];
  #pragma unroll 4
  for (int d = 0; d < ND; ++d) acc = fmaf(xs[d], Wq[d * NKD + lane], acc);
  unsigned short h = f2bf(acc);
  Qh[(size_t)row * NKD + lane] = h;
  Ql[(size_t)row * NKD + lane] = f2bf(acc - bf2f(h));
}

// =====================================================================
// K2: FUSED per-(b,t): K-proj + V-proj -> LDS, then attention.
// 1024 thr (16 waves), grid 512, LDS 128 KB:
//   [0..64K)    Kh[256 j][64 kd] / Kl  (bf16, 16B-blk swizzle: blk ^ (j&7))
//   [64K..128K) Vth[64 vd][256 j] / Vtl (swizzle: blk ^ (vd&7))
// EXACTLY ONE barrier: phases A/B write disjoint LDS slices; after the
// barrier LDS is read-only (P redistribution is in-register via shfl),
// so the kernel is structurally race-free.
// =====================================================================
__global__ __launch_bounds__(1024) void k_fused(
    const float* __restrict__ Xm, const float* __restrict__ Ym,
    const unsigned short* __restrict__ Wkth, const unsigned short* __restrict__ Wktl,
    const unsigned short* __restrict__ Wvth, const unsigned short* __restrict__ Wvtl,
    const float* __restrict__ bk, const float* __restrict__ bv,
    const unsigned short* __restrict__ Qh, const unsigned short* __restrict__ Ql,
    unsigned short* __restrict__ R,      // [bt][256 i][64 vd] bf16
    float* __restrict__ Sc) {            // [bt][256 i] raw row max
  __shared__ uint4 smem4[8192];          // 128 KB
  char* smemb = (char*)smem4;
  int tid = threadIdx.x;
  int bt = blockIdx.x, b = bt >> 6;
  int w = tid >> 6, lane = tid & 63, c = lane & 15, g = lane >> 4;

  // ---------------- Phase A: K-proj (swapped: m=kd, n=j) ----------------
  {
    const float* xrow = Xm + (size_t)bt * 65536 + (size_t)(w * 16 + c) * 256 + g * 8;
    f32x4 acc[4];
    #pragma unroll
    for (int mf = 0; mf < 4; ++mf) acc[mf] = (f32x4)0.f;
    float4 xp0 = *(const float4*)(xrow);
    float4 xp1 = *(const float4*)(xrow + 4);
    #pragma unroll 2
    for (int ks = 0; ks < 8; ++ks) {
      float xc[8];
      *(float4*)&xc[0] = xp0;
      *(float4*)&xc[4] = xp1;
      if (ks < 7) {                       // prefetch next X chunk
        xp0 = *(const float4*)(xrow + (ks + 1) * 32);
        xp1 = *(const float4*)(xrow + (ks + 1) * 32 + 4);
      }
      bf16x8 bxh, bxl;
      split8(xc, bxh, bxl);
      int k0 = ks * 32;
      #pragma unroll
      for (int mf = 0; mf < 4; ++mf) {
        size_t off = (size_t)(mf * 16 + c) * 256 + k0 + g * 8;
        bf16x8 awh = *(const bf16x8*)(Wkth + off);
        bf16x8 awl = *(const bf16x8*)(Wktl + off);
        acc[mf] = MFMA16(awh, bxh, acc[mf]);
        acc[mf] = MFMA16(awl, bxh, acc[mf]);
        acc[mf] = MFMA16(awh, bxl, acc[mf]);
      }
    }
    int j = w * 16 + c;
    #pragma unroll
    for (int mf = 0; mf < 4; ++mf) {      // element (kd = mf*16+4g+r, j)
      bf16x4 ph, plo4;
      #pragma unroll
      for (int r = 0; r < 4; ++r) {
        float v = acc[mf][r] + bk[mf * 16 + g * 4 + r];
        unsigned short h = f2bf(v);
        ph[r] = (short)h;
        plo4[r] = (short)f2bf(v - bf2f(h));
      }
      int ba = j * 128 + ((((mf * 2) + (g >> 1)) ^ (j & 7)) << 4) + (g & 1) * 8;
      *(bf16x4*)(smemb + ba) = ph;
      *(bf16x4*)(smemb + 32768 + ba) = plo4;
    }
  }

  // ---------------- Phase B: V-proj (normal: m=j, n=vd) -----------------
  {
    const float* yrow = Ym + (size_t)bt * 65536 + (size_t)(w * 16 + c) * 256 + g * 8;
    f32x4 acc[4];
    #pragma unroll
    for (int nf = 0; nf < 4; ++nf) acc[nf] = (f32x4)0.f;
    float4 yp0 = *(const float4*)(yrow);
    float4 yp1 = *(const float4*)(yrow + 4);
    #pragma unroll 2
    for (int ks = 0; ks < 8; ++ks) {
      float yc[8];
      *(float4*)&yc[0] = yp0;
      *(float4*)&yc[4] = yp1;
      if (ks < 7) {
        yp0 = *(const float4*)(yrow + (ks + 1) * 32);
        yp1 = *(const float4*)(yrow + (ks + 1) * 32 + 4);
      }
      bf16x8 axh, axl;
      split8(yc, axh, axl);
      int k0 = ks * 32;
      #pragma unroll
      for (int nf = 0; nf < 4; ++nf) {
        size_t off = (size_t)(nf * 16 + c) * 256 + k0 + g * 8;
        bf16x8 bwh = *(const bf16x8*)(Wvth + off);
        bf16x8 bwl = *(const bf16x8*)(Wvtl + off);
        acc[nf] = MFMA16(axh, bwh, acc[nf]);
        acc[nf] = MFMA16(axl, bwh, acc[nf]);
        acc[nf] = MFMA16(axh, bwl, acc[nf]);
      }
    }
    #pragma unroll
    for (int nf = 0; nf < 4; ++nf) {      // element (j = w*16+4g+r, vd = nf*16+c)
      int vd = nf * 16 + c;
      float bs = bv[vd];
      bf16x4 ph, plo4;
      #pragma unroll
      for (int r = 0; r < 4; ++r) {
        float v = acc[nf][r] + bs;
        unsigned short h = f2bf(v);
        ph[r] = (short)h;
        plo4[r] = (short)f2bf(v - bf2f(h));
      }
      int ba = 65536 + vd * 512 + (((w * 2 + (g >> 1)) ^ (vd & 7)) << 4) + (g & 1) * 8;
      *(bf16x4*)(smemb + ba) = ph;
      *(bf16x4*)(smemb + ba + 32768) = plo4;
    }
  }

  // Q B-frags from global (L2-hot) — issue before the barrier
  bf16x8 qbh[2], qbl[2];
  #pragma unroll
  for (int ks = 0; ks < 2; ++ks) {
    size_t qo = ((size_t)b * NI + w * 16 + c) * NKD + ks * 32 + g * 8;
    qbh[ks] = *(const bf16x8*)(Qh + qo);
    qbl[ks] = *(const bf16x8*)(Ql + qo);
  }
  __syncthreads();   // the ONLY barrier: LDS is read-only from here on

  // ---------------- Phase C: S^T = K * Q^T ------------------------------
  // sa[jf] holds S^T[j = 16jf+4g+r][i = w*16+c]
  f32x4 sa[16];
  #pragma unroll
  for (int jf = 0; jf < 16; ++jf) sa[jf] = (f32x4)0.f;
  #pragma unroll
  for (int jf = 0; jf < 16; ++jf) {
    int j = jf * 16 + c;
    #pragma unroll
    for (int ks = 0; ks < 2; ++ks) {
      int ba = j * 128 + (((ks * 4 + g) ^ (j & 7)) << 4);
      bf16x8 kh = *(const bf16x8*)(smemb + ba);
      bf16x8 kl = *(const bf16x8*)(smemb + 32768 + ba);
      sa[jf] = MFMA16(kh, qbh[ks], sa[jf]);
      sa[jf] = MFMA16(kl, qbh[ks], sa[jf]);
      sa[jf] = MFMA16(kh, qbl[ks], sa[jf]);
    }
  }

  // softmax over j for column i = w*16 + c (lane-local + 2 shfl)
  float mx = sa[0][0];
  #pragma unroll
  for (int jf = 0; jf < 16; ++jf)
    #pragma unroll
    for (int r = 0; r < 4; ++r) mx = fmaxf(mx, sa[jf][r]);
  mx = fmaxf(mx, __shfl_xor(mx, 16));
  mx = fmaxf(mx, __shfl_xor(mx, 32));
  if (g == 0) Sc[(size_t)bt * NI + w * 16 + c] = mx;   // raw max
  float sum = 0.f;
  #pragma unroll
  for (int jf = 0; jf < 16; ++jf)
    #pragma unroll
    for (int r = 0; r < 4; ++r) {
      float p = __expf((sa[jf][r] - mx) * SCL);
      sa[jf][r] = p;
      sum += p;
    }
  sum += __shfl_xor(sum, 16);
  sum += __shfl_xor(sum, 32);
  float linv = 1.0f / sum;

  // pack P (unnormalized) into bf16-pair words: plo/phi[jf] = j {16jf+4g+0,1}/{2,3}
  unsigned int plo[16], phi[16];
  #pragma unroll
  for (int jf = 0; jf < 16; ++jf) {
    plo[jf] = (unsigned int)f2bf(sa[jf][0]) | ((unsigned int)f2bf(sa[jf][1]) << 16);
    phi[jf] = (unsigned int)f2bf(sa[jf][2]) | ((unsigned int)f2bf(sa[jf][3]) << 16);
  }

  // In-register P^T redistribution (replaces LDS bounce):
  // target lane (c,g), step js needs P^T[32js+8g+e][i=c] = words
  // {plo,phi}[2js + (g>>1)] of source lanes srcA = c+32(g&1), srcB = srcA+16.
  int srcA = c + 32 * (g & 1);
  int srcB = srcA + 16;
  bool hiH = (g >= 2);

  f32x4 racc[4];
  #pragma unroll
  for (int vf = 0; vf < 4; ++vf) racc[vf] = (f32x4)0.f;

  #pragma unroll
  for (int js = 0; js < 8; ++js) {
    int a0 = __shfl((int)plo[2 * js], srcA);
    int a1 = __shfl((int)phi[2 * js], srcA);
    int a2 = __shfl((int)plo[2 * js], srcB);
    int a3 = __shfl((int)phi[2 * js], srcB);
    int b0 = __shfl((int)plo[2 * js + 1], srcA);
    int b1 = __shfl((int)phi[2 * js + 1], srcA);
    int b2 = __shfl((int)plo[2 * js + 1], srcB);
    int b3 = __shfl((int)phi[2 * js + 1], srcB);
    uint32x4 pw;
    pw[0] = (unsigned int)(hiH ? b0 : a0);
    pw[1] = (unsigned int)(hiH ? b1 : a1);
    pw[2] = (unsigned int)(hiH ? b2 : a2);
    pw[3] = (unsigned int)(hiH ? b3 : a3);
    bf16x8 pf = __builtin_bit_cast(bf16x8, pw);
    #pragma unroll
    for (int vf = 0; vf < 4; ++vf) {
      int vd = vf * 16 + c;
      int vba = 65536 + vd * 512 + (((js * 4 + g) ^ (vd & 7)) << 4);
      bf16x8 vh = *(const bf16x8*)(smemb + vba);
      bf16x8 vl = *(const bf16x8*)(smemb + vba + 32768);
      racc[vf] = MFMA16(vh, pf, racc[vf]);
      racc[vf] = MFMA16(vl, pf, racc[vf]);
    }
  }

  // write R[bt][i][vd] bf16, normalized; element (vd = vf*16+4g+r, i = w*16+c)
  int i = w * 16 + c;
  #pragma unroll
  for (int vf = 0; vf < 4; ++vf) {
    bf16x4 rk;
    #pragma unroll
    for (int r = 0; r < 4; ++r) rk[r] = (short)f2bf(racc[vf][r] * linv);
    *(bf16x4*)(R + ((size_t)bt * NI + i) * NKD + vf * 16 + g * 4) = rk;
  }
}

// =====================================================================
// K3: level-2 attention over t. grid = NB*NI, 64 thr. lane = t then vd.
// =====================================================================
__global__ __launch_bounds__(64) void k_level2(
    const float* __restrict__ Sc,         // [bt][256]
    const unsigned short* __restrict__ R, // [bt][256][64] bf16
    float* __restrict__ out) {            // [b][256][64] f32
  int bi = blockIdx.x;
  int b = bi >> 8, i = bi & 255;
  int lane = threadIdx.x;
  float sc = Sc[((size_t)b * NT + lane) * NI + i];
  float mx = sc;
  #pragma unroll
  for (int off = 32; off; off >>= 1) mx = fmaxf(mx, __shfl_xor(mx, off));
  float e = __expf((sc - mx) * SCL);
  float sum = e;
  #pragma unroll
  for (int off = 32; off; off >>= 1) sum += __shfl_xor(sum, off);
  float wn = e / sum;
  float acc = 0.f;
  for (int t = 0; t < NT; ++t) {
    float wt = __shfl(wn, t);
    acc = fmaf(wt, bf2f(R[(((size_t)b * NT + t) * NI + i) * NKD + lane]), acc);
  }
  out[((size_t)b * NI + i) * NVD + lane] = acc;
}

// =====================================================================
extern "C" void kernel_launch(void* const* d_in, const int* in_sizes, int n_in,
                              void* d_out, int out_size, void* d_ws, size_t ws_size,
                              hipStream_t stream) {
  const float* x   = (const float*)d_in[0];
  const float* mxp = (const float*)d_in[1];
  const float* myp = (const float*)d_in[2];
  const float* Wq  = (const float*)d_in[3];
  const float* bq  = (const float*)d_in[4];
  const float* Wk  = (const float*)d_in[5];
  const float* bk  = (const float*)d_in[6];
  const float* Wv  = (const float*)d_in[7];
  const float* bv  = (const float*)d_in[8];
  float* out = (float*)d_out;

  // workspace carve (~18 MB)
  char* p = (char*)d_ws;
  auto alloc = [&](size_t bytes) { char* r = p; p += (bytes + 255) & ~(size_t)255; return r; };
  unsigned short* Qh   = (unsigned short*)alloc(2048 * 64 * 2);
  unsigned short* Ql   = (unsigned short*)alloc(2048 * 64 * 2);
  unsigned short* Rw   = (unsigned short*)alloc((size_t)131072 * 64 * 2);
  float*          Scw  = (float*)alloc((size_t)131072 * 4);
  unsigned short* Wkth = (unsigned short*)alloc(64 * 256 * 2);
  unsigned short* Wktl = (unsigned short*)alloc(64 * 256 * 2);
  unsigned short* Wvth = (unsigned short*)alloc(64 * 256 * 2);
  unsigned short* Wvtl = (unsigned short*)alloc(64 * 256 * 2);

  hipLaunchKernelGGL(k_prep_wt, dim3(64), dim3(256), 0, stream,
                     Wk, Wv, Wkth, Wktl, Wvth, Wvtl);
  hipLaunchKernelGGL(k_proj_q, dim3(NB * NI), dim3(64), 0, stream, x, Wq, bq, Qh, Ql);
  hipLaunchKernelGGL(k_fused, dim3(NB * NT), dim3(1024), 0, stream,
                     mxp, myp, Wkth, Wktl, Wvth, Wvtl, bk, bv, Qh, Ql, Rw, Scw);
  hipLaunchKernelGGL(k_level2, dim3(NB * NI), dim3(64), 0, stream, Scw, Rw, out);
}

// Round 6
// 157.813 us; speedup vs baseline: 2.3008x; 1.3187x over previous
//
#include <hip/hip_runtime.h>
#include <hip/hip_bf16.h>

// Shapes (fixed)
#define NB 8
#define NT 64
#define NI 256
#define NJ 256
#define ND 256
#define NKD 64
#define NVD 64
#define SCL 0.125f   // 1/sqrt(64), both attention levels

typedef __attribute__((ext_vector_type(4))) float f32x4;
typedef __attribute__((ext_vector_type(8))) short bf16x8;  // 8 bf16 = 4 VGPR (MFMA A/B frag)
typedef __attribute__((ext_vector_type(4))) short bf16x4;  // 4 bf16 = 8 B packed store
typedef __attribute__((ext_vector_type(4))) unsigned int uint32x4;

// D[16 M][16 N] = A[16 M][32 K] * B[32 K][16 N] + C
// A frag: lane l holds A[l%16][8*(l/16)+e] ; B frag: B[8*(l/16)+e][l%16]
// C/D:    lane l holds D[4*(l/16)+r][l%16]
#define MFMA16(A, B, C) __builtin_amdgcn_mfma_f32_16x16x32_bf16((A), (B), (C), 0, 0, 0)

__device__ __forceinline__ unsigned short f2bf(float x) {   // RNE
  return __builtin_bit_cast(unsigned short, __float2bfloat16(x));
}
__device__ __forceinline__ float bf2f(unsigned short h) {
  return __builtin_bit_cast(float, (unsigned)h << 16);
}
// split fp32 -> hi + lo bf16; hi+lo = x to ~2^-18 rel
__device__ __forceinline__ void split8(const float* __restrict__ x, bf16x8& hi, bf16x8& lo) {
  #pragma unroll
  for (int e = 0; e < 8; ++e) {
    unsigned short h = f2bf(x[e]);
    hi[e] = (short)h;
    lo[e] = (short)f2bf(x[e] - bf2f(h));
  }
}

// =====================================================================
// K0: pre-transpose + split weights:  W[256][64] -> Wt_hi/lo[64][256]
// =====================================================================
__global__ __launch_bounds__(256) void k_prep_wt(
    const float* __restrict__ Wk, const float* __restrict__ Wv,
    unsigned short* __restrict__ Wkth, unsigned short* __restrict__ Wktl,
    unsigned short* __restrict__ Wvth, unsigned short* __restrict__ Wvtl) {
  int t = blockIdx.x * 256 + threadIdx.x;   // 0..16383
  int d = t >> 6, kd = t & 63;
  float x = Wk[t];
  unsigned short h = f2bf(x);
  Wkth[kd * 256 + d] = h;
  Wktl[kd * 256 + d] = f2bf(x - bf2f(h));
  x = Wv[t];
  h = f2bf(x);
  Wvth[kd * 256 + d] = h;
  Wvtl[kd * 256 + d] = f2bf(x - bf2f(h));
}

// =====================================================================
// K1: Q = input_seq @ Wq + bq  (fp32 compute), output split bf16 hi/lo
// =====================================================================
__global__ __launch_bounds__(64) void k_proj_q(
    const float* __restrict__ x, const float* __restrict__ Wq,
    const float* __restrict__ bq,
    unsigned short* __restrict__ Qh, unsigned short* __restrict__ Ql) {
  int row = blockIdx.x, lane = threadIdx.x;
  __shared__ __align__(16) float xs[ND];
  const float* xr = x + (size_t)row * ND;
  #pragma unroll
  for (int cc = 0; cc < 4; ++cc) xs[lane + 64 * cc] = xr[lane + 64 * cc];
  __syncthreads();
  float acc = bq[lane];
  #pragma unroll 4
  for (int d = 0; d < ND; ++d) acc = fmaf(xs[d], Wq[d * NKD + lane], acc);
  unsigned short h = f2bf(acc);
  Qh[(size_t)row * NKD + lane] = h;
  Ql[(size_t)row * NKD + lane] = f2bf(acc - bf2f(h));
}

// =====================================================================
// W-plane LDS staging (both proj kernels): 2 planes x 32 KB = 64 KB.
// Plane row r (=kd, 0..63) is 512 B = 32 16B-chunks, swizzle blk ^ (r&7).
// Fragment read: row f*16+c, chunk ks*4+g -> blk (ks*4+g)^(r&7).
// 512-thread blocks: 2048 chunks/plane staged in 4 sweeps.
// =====================================================================
__device__ __forceinline__ void stage_w(
    char* wl, const unsigned short* __restrict__ Wth,
    const unsigned short* __restrict__ Wtl, int tid) {
  #pragma unroll
  for (int it = 0; it < 4; ++it) {
    int qq = tid + it * 512;            // 16B chunk id, 0..2047
    int r = qq >> 5, pb = qq & 31;
    uint4 vh = *(const uint4*)((const char*)Wth + (size_t)qq * 16);
    uint4 vl = *(const uint4*)((const char*)Wtl + (size_t)qq * 16);
    int dst = r * 512 + ((pb ^ (r & 7)) << 4);
    *(uint4*)(wl + dst) = vh;
    *(uint4*)(wl + 32768 + dst) = vl;
  }
}

// =====================================================================
// K2a: K-projection (swapped: M=kd, N=j):  D[kd][j] = Wkt x X^T (+bk)
// out: Kh/Kl[bt*256 + j][64]. 512 thr (8 waves), one bt (256 j) per
// block, grid 512. W staged in LDS (64 KB); X streamed with prefetch-1.
// =====================================================================
__global__ __launch_bounds__(512) void k_proj_k(
    const float* __restrict__ X,
    const unsigned short* __restrict__ Wth, const unsigned short* __restrict__ Wtl,
    const float* __restrict__ bias,
    unsigned short* __restrict__ Kh, unsigned short* __restrict__ Kl) {
  __shared__ __align__(16) char wl[65536];
  int tid = threadIdx.x;
  stage_w(wl, Wth, Wtl, tid);
  int w = tid >> 6, lane = tid & 63, c = lane & 15, g = lane >> 4;
  size_t j0w = (size_t)blockIdx.x * 256 + w * 32;
  __syncthreads();   // LDS read-only after this point

  f32x4 acc[4][2];
  #pragma unroll
  for (int mf = 0; mf < 4; ++mf) { acc[mf][0] = (f32x4)0.f; acc[mf][1] = (f32x4)0.f; }

  const float* xr0 = X + (j0w + c) * 256 + g * 8;        // B row nf=0
  const float* xr1 = X + (j0w + 16 + c) * 256 + g * 8;   // B row nf=1
  float4 p00 = *(const float4*)xr0, p01 = *(const float4*)(xr0 + 4);
  float4 p10 = *(const float4*)xr1, p11 = *(const float4*)(xr1 + 4);
  #pragma unroll
  for (int ks = 0; ks < 8; ++ks) {
    float x0[8], x1[8];
    *(float4*)&x0[0] = p00; *(float4*)&x0[4] = p01;
    *(float4*)&x1[0] = p10; *(float4*)&x1[4] = p11;
    if (ks < 7) {
      p00 = *(const float4*)(xr0 + (ks + 1) * 32);
      p01 = *(const float4*)(xr0 + (ks + 1) * 32 + 4);
      p10 = *(const float4*)(xr1 + (ks + 1) * 32);
      p11 = *(const float4*)(xr1 + (ks + 1) * 32 + 4);
    }
    bf16x8 b0h, b0l, b1h, b1l;
    split8(x0, b0h, b0l);
    split8(x1, b1h, b1l);
    #pragma unroll
    for (int mf = 0; mf < 4; ++mf) {
      int r = mf * 16 + c;
      int ba = r * 512 + (((ks * 4 + g) ^ (r & 7)) << 4);
      bf16x8 awh = *(const bf16x8*)(wl + ba);
      bf16x8 awl = *(const bf16x8*)(wl + 32768 + ba);
      acc[mf][0] = MFMA16(awh, b0h, acc[mf][0]);
      acc[mf][0] = MFMA16(awl, b0h, acc[mf][0]);
      acc[mf][0] = MFMA16(awh, b0l, acc[mf][0]);
      acc[mf][1] = MFMA16(awh, b1h, acc[mf][1]);
      acc[mf][1] = MFMA16(awl, b1h, acc[mf][1]);
      acc[mf][1] = MFMA16(awh, b1l, acc[mf][1]);
    }
  }
  #pragma unroll
  for (int nf = 0; nf < 2; ++nf) {
    size_t j = j0w + nf * 16 + c;
    #pragma unroll
    for (int mf = 0; mf < 4; ++mf) {   // element (kd = mf*16+4g+r, j)
      bf16x4 ph, pl4;
      #pragma unroll
      for (int r = 0; r < 4; ++r) {
        float v = acc[mf][nf][r] + bias[mf * 16 + g * 4 + r];
        unsigned short h = f2bf(v);
        ph[r] = (short)h;
        pl4[r] = (short)f2bf(v - bf2f(h));
      }
      *(bf16x4*)(Kh + j * NKD + mf * 16 + g * 4) = ph;
      *(bf16x4*)(Kl + j * NKD + mf * 16 + g * 4) = pl4;
    }
  }
}

// =====================================================================
// K2b: V-projection (normal: M=j, N=vd):  D[j][vd] = Y x Wv (+bv)
// out TRANSPOSED: Vth/Vtl[bt*64 + vd][256 j]. Same block shape as K2a.
// =====================================================================
__global__ __launch_bounds__(512) void k_proj_v(
    const float* __restrict__ Y,
    const unsigned short* __restrict__ Wth, const unsigned short* __restrict__ Wtl,
    const float* __restrict__ bias,
    unsigned short* __restrict__ Vth, unsigned short* __restrict__ Vtl) {
  __shared__ __align__(16) char wl[65536];
  int tid = threadIdx.x;
  stage_w(wl, Wth, Wtl, tid);
  int w = tid >> 6, lane = tid & 63, c = lane & 15, g = lane >> 4;
  size_t row0w = (size_t)blockIdx.x * 256 + w * 32;
  __syncthreads();

  f32x4 acc[2][4];
  #pragma unroll
  for (int mf = 0; mf < 2; ++mf)
    #pragma unroll
    for (int nf = 0; nf < 4; ++nf) acc[mf][nf] = (f32x4)0.f;

  const float* yr0 = Y + (row0w + c) * 256 + g * 8;        // A row mf=0
  const float* yr1 = Y + (row0w + 16 + c) * 256 + g * 8;   // A row mf=1
  float4 p00 = *(const float4*)yr0, p01 = *(const float4*)(yr0 + 4);
  float4 p10 = *(const float4*)yr1, p11 = *(const float4*)(yr1 + 4);
  #pragma unroll
  for (int ks = 0; ks < 8; ++ks) {
    float y0[8], y1[8];
    *(float4*)&y0[0] = p00; *(float4*)&y0[4] = p01;
    *(float4*)&y1[0] = p10; *(float4*)&y1[4] = p11;
    if (ks < 7) {
      p00 = *(const float4*)(yr0 + (ks + 1) * 32);
      p01 = *(const float4*)(yr0 + (ks + 1) * 32 + 4);
      p10 = *(const float4*)(yr1 + (ks + 1) * 32);
      p11 = *(const float4*)(yr1 + (ks + 1) * 32 + 4);
    }
    bf16x8 a0h, a0l, a1h, a1l;
    split8(y0, a0h, a0l);
    split8(y1, a1h, a1l);
    #pragma unroll
    for (int nf = 0; nf < 4; ++nf) {
      int r = nf * 16 + c;
      int ba = r * 512 + (((ks * 4 + g) ^ (r & 7)) << 4);
      bf16x8 bwh = *(const bf16x8*)(wl + ba);
      bf16x8 bwl = *(const bf16x8*)(wl + 32768 + ba);
      acc[0][nf] = MFMA16(a0h, bwh, acc[0][nf]);
      acc[0][nf] = MFMA16(a0l, bwh, acc[0][nf]);
      acc[0][nf] = MFMA16(a0h, bwl, acc[0][nf]);
      acc[1][nf] = MFMA16(a1h, bwh, acc[1][nf]);
      acc[1][nf] = MFMA16(a1l, bwh, acc[1][nf]);
      acc[1][nf] = MFMA16(a1h, bwl, acc[1][nf]);
    }
  }
  size_t bt = row0w >> 8;
  int jl0 = (int)(row0w & 255);
  #pragma unroll
  for (int nf = 0; nf < 4; ++nf) {
    int vd = nf * 16 + c;
    float bs = bias[vd];
    #pragma unroll
    for (int mf = 0; mf < 2; ++mf) {   // element (j = jl0+mf*16+4g+r, vd)
      bf16x4 ph, pl4;
      #pragma unroll
      for (int r = 0; r < 4; ++r) {
        float v = acc[mf][nf][r] + bs;
        unsigned short h = f2bf(v);
        ph[r] = (short)h;
        pl4[r] = (short)f2bf(v - bf2f(h));
      }
      size_t off = ((size_t)bt * NKD + vd) * NJ + jl0 + mf * 16 + g * 4;
      *(bf16x4*)(Vth + off) = ph;
      *(bf16x4*)(Vtl + off) = pl4;
    }
  }
}

// =====================================================================
// K3: attention per (b,t). 512 thr (8 waves), grid 512, LDS 128 KB:
//   [0..64K)    Kh[256 j][64 kd] / Kl  (16B-blk swizzle: blk ^ (j&7))
//   [64K..128K) Vth[64 vd][256 j] / Vtl (swizzle: blk ^ (vd&7))
// ONE barrier after staging; LDS read-only after (P redistribution is
// in-register via shfl) -> structurally race-free.
// Wave w owns i-range w*32..w*32+32, two ic slabs of 16.
// =====================================================================
__global__ __launch_bounds__(512) void k_attn(
    const unsigned short* __restrict__ Qh, const unsigned short* __restrict__ Ql,
    const unsigned short* __restrict__ Kh, const unsigned short* __restrict__ Kl,
    const unsigned short* __restrict__ Vth, const unsigned short* __restrict__ Vtl,
    unsigned short* __restrict__ R,      // [bt][256 i][64 vd] bf16
    float* __restrict__ Sc) {            // [bt][256 i] raw row max
  __shared__ uint4 smem4[8192];          // 128 KB
  char* smemb = (char*)smem4;
  int tid = threadIdx.x;
  int bt = blockIdx.x, b = bt >> 6;
  int w = tid >> 6, lane = tid & 63, c = lane & 15, g = lane >> 4;

  // ---- stage the 4 planes (reg-staged, swizzled ds_write) ----
  #pragma unroll
  for (int pl = 0; pl < 4; ++pl) {
    const unsigned short* src =
        (pl == 0) ? Kh + (size_t)bt * 16384 :
        (pl == 1) ? Kl + (size_t)bt * 16384 :
        (pl == 2) ? Vth + (size_t)bt * 16384 :
                    Vtl + (size_t)bt * 16384;
    #pragma unroll
    for (int it = 0; it < 4; ++it) {
      int qq = tid + it * 512;           // 16B chunk id within plane (0..2047)
      uint4 v = *(const uint4*)((const char*)src + (size_t)qq * 16);
      int dst;
      if (pl < 2) { int j = qq >> 3;  int pb = qq & 7;  dst = pl * 32768 + j * 128 + ((pb ^ (j & 7)) << 4); }
      else        { int vd = qq >> 5; int pb = qq & 31; dst = pl * 32768 + vd * 512 + ((pb ^ (vd & 7)) << 4); }
      *(uint4*)(smemb + dst) = v;
    }
  }
  __syncthreads();   // the ONLY barrier: LDS read-only from here on

  #pragma unroll
  for (int ic = 0; ic < 2; ++ic) {
    int i = w * 32 + ic * 16 + c;
    // Q B-frags (global, L2-hot)
    bf16x8 qbh[2], qbl[2];
    #pragma unroll
    for (int ks = 0; ks < 2; ++ks) {
      size_t qo = ((size_t)b * NI + i) * NKD + ks * 32 + g * 8;
      qbh[ks] = *(const bf16x8*)(Qh + qo);
      qbl[ks] = *(const bf16x8*)(Ql + qo);
    }

    // ---- S^T = K * Q^T : sa[jf] holds S^T[j = 16jf+4g+r][i] ----
    f32x4 sa[16];
    #pragma unroll
    for (int jf = 0; jf < 16; ++jf) sa[jf] = (f32x4)0.f;
    #pragma unroll
    for (int jf = 0; jf < 16; ++jf) {
      int j = jf * 16 + c;
      #pragma unroll
      for (int ks = 0; ks < 2; ++ks) {
        int ba = j * 128 + (((ks * 4 + g) ^ (j & 7)) << 4);
        bf16x8 kh = *(const bf16x8*)(smemb + ba);
        bf16x8 kl = *(const bf16x8*)(smemb + 32768 + ba);
        sa[jf] = MFMA16(kh, qbh[ks], sa[jf]);
        sa[jf] = MFMA16(kl, qbh[ks], sa[jf]);
        sa[jf] = MFMA16(kh, qbl[ks], sa[jf]);
      }
    }

    // ---- softmax over j (lane-local + 2 shfl) ----
    float mx = sa[0][0];
    #pragma unroll
    for (int jf = 0; jf < 16; ++jf)
      #pragma unroll
      for (int r = 0; r < 4; ++r) mx = fmaxf(mx, sa[jf][r]);
    mx = fmaxf(mx, __shfl_xor(mx, 16));
    mx = fmaxf(mx, __shfl_xor(mx, 32));
    if (g == 0) Sc[(size_t)bt * NI + i] = mx;   // raw max
    float sum = 0.f;
    #pragma unroll
    for (int jf = 0; jf < 16; ++jf)
      #pragma unroll
      for (int r = 0; r < 4; ++r) {
        float p = __expf((sa[jf][r] - mx) * SCL);
        sa[jf][r] = p;
        sum += p;
      }
    sum += __shfl_xor(sum, 16);
    sum += __shfl_xor(sum, 32);
    float linv = 1.0f / sum;

    // pack P into bf16-pair words: plo/phi[jf] = j {16jf+4g+0,1}/{2,3}
    unsigned int plo[16], phi[16];
    #pragma unroll
    for (int jf = 0; jf < 16; ++jf) {
      plo[jf] = (unsigned int)f2bf(sa[jf][0]) | ((unsigned int)f2bf(sa[jf][1]) << 16);
      phi[jf] = (unsigned int)f2bf(sa[jf][2]) | ((unsigned int)f2bf(sa[jf][3]) << 16);
    }

    // in-register P^T redistribution: target lane (c,g), step js needs
    // words {plo,phi}[2js + (g>>1)] of lanes srcA = c+32(g&1), srcB = srcA+16
    int srcA = c + 32 * (g & 1);
    int srcB = srcA + 16;
    bool hiH = (g >= 2);

    f32x4 racc[4];
    #pragma unroll
    for (int vf = 0; vf < 4; ++vf) racc[vf] = (f32x4)0.f;
    #pragma unroll
    for (int js = 0; js < 8; ++js) {
      int a0 = __shfl((int)plo[2 * js], srcA);
      int a1 = __shfl((int)phi[2 * js], srcA);
      int a2 = __shfl((int)plo[2 * js], srcB);
      int a3 = __shfl((int)phi[2 * js], srcB);
      int b0 = __shfl((int)plo[2 * js + 1], srcA);
      int b1 = __shfl((int)phi[2 * js + 1], srcA);
      int b2 = __shfl((int)plo[2 * js + 1], srcB);
      int b3 = __shfl((int)phi[2 * js + 1], srcB);
      uint32x4 pw;
      pw[0] = (unsigned int)(hiH ? b0 : a0);
      pw[1] = (unsigned int)(hiH ? b1 : a1);
      pw[2] = (unsigned int)(hiH ? b2 : a2);
      pw[3] = (unsigned int)(hiH ? b3 : a3);
      bf16x8 pf = __builtin_bit_cast(bf16x8, pw);
      #pragma unroll
      for (int vf = 0; vf < 4; ++vf) {
        int vd = vf * 16 + c;
        int vba = 65536 + vd * 512 + (((js * 4 + g) ^ (vd & 7)) << 4);
        bf16x8 vh = *(const bf16x8*)(smemb + vba);
        bf16x8 vl = *(const bf16x8*)(smemb + vba + 32768);
        racc[vf] = MFMA16(vh, pf, racc[vf]);
        racc[vf] = MFMA16(vl, pf, racc[vf]);
      }
    }

    // write R[bt][i][vd] bf16, normalized; element (vd = vf*16+4g+r, i)
    #pragma unroll
    for (int vf = 0; vf < 4; ++vf) {
      bf16x4 rk;
      #pragma unroll
      for (int r = 0; r < 4; ++r) rk[r] = (short)f2bf(racc[vf][r] * linv);
      *(bf16x4*)(R + ((size_t)bt * NI + i) * NKD + vf * 16 + g * 4) = rk;
    }
  }
}

// =====================================================================
// K4: level-2 attention over t. grid = NB*NI, 64 thr. lane = t then vd.
// =====================================================================
__global__ __launch_bounds__(64) void k_level2(
    const float* __restrict__ Sc,         // [bt][256]
    const unsigned short* __restrict__ R, // [bt][256][64] bf16
    float* __restrict__ out) {            // [b][256][64] f32
  int bi = blockIdx.x;
  int b = bi >> 8, i = bi & 255;
  int lane = threadIdx.x;
  float sc = Sc[((size_t)b * NT + lane) * NI + i];
  float mx = sc;
  #pragma unroll
  for (int off = 32; off; off >>= 1) mx = fmaxf(mx, __shfl_xor(mx, off));
  float e = __expf((sc - mx) * SCL);
  float sum = e;
  #pragma unroll
  for (int off = 32; off; off >>= 1) sum += __shfl_xor(sum, off);
  float wn = e / sum;
  float acc = 0.f;
  for (int t = 0; t < NT; ++t) {
    float wt = __shfl(wn, t);
    acc = fmaf(wt, bf2f(R[(((size_t)b * NT + t) * NI + i) * NKD + lane]), acc);
  }
  out[((size_t)b * NI + i) * NVD + lane] = acc;
}

// =====================================================================
extern "C" void kernel_launch(void* const* d_in, const int* in_sizes, int n_in,
                              void* d_out, int out_size, void* d_ws, size_t ws_size,
                              hipStream_t stream) {
  const float* x   = (const float*)d_in[0];
  const float* mxp = (const float*)d_in[1];
  const float* myp = (const float*)d_in[2];
  const float* Wq  = (const float*)d_in[3];
  const float* bq  = (const float*)d_in[4];
  const float* Wk  = (const float*)d_in[5];
  const float* bk  = (const float*)d_in[6];
  const float* Wv  = (const float*)d_in[7];
  const float* bv  = (const float*)d_in[8];
  float* out = (float*)d_out;

  // workspace carve (~82 MB)
  char* p = (char*)d_ws;
  auto alloc = [&](size_t bytes) { char* r = p; p += (bytes + 255) & ~(size_t)255; return r; };
  unsigned short* Qh   = (unsigned short*)alloc(2048 * 64 * 2);
  unsigned short* Ql   = (unsigned short*)alloc(2048 * 64 * 2);
  unsigned short* Khw  = (unsigned short*)alloc((size_t)131072 * 64 * 2);
  unsigned short* Klw  = (unsigned short*)alloc((size_t)131072 * 64 * 2);
  unsigned short* Vthw = (unsigned short*)alloc((size_t)131072 * 64 * 2);
  unsigned short* Vtlw = (unsigned short*)alloc((size_t)131072 * 64 * 2);
  unsigned short* Rw   = (unsigned short*)alloc((size_t)131072 * 64 * 2);
  float*          Scw  = (float*)alloc((size_t)131072 * 4);
  unsigned short* Wkth = (unsigned short*)alloc(64 * 256 * 2);
  unsigned short* Wktl = (unsigned short*)alloc(64 * 256 * 2);
  unsigned short* Wvth = (unsigned short*)alloc(64 * 256 * 2);
  unsigned short* Wvtl = (unsigned short*)alloc(64 * 256 * 2);

  hipLaunchKernelGGL(k_prep_wt, dim3(64), dim3(256), 0, stream,
                     Wk, Wv, Wkth, Wktl, Wvth, Wvtl);
  hipLaunchKernelGGL(k_proj_q, dim3(NB * NI), dim3(64), 0, stream, x, Wq, bq, Qh, Ql);
  hipLaunchKernelGGL(k_proj_k, dim3(NB * NT), dim3(512), 0, stream,
                     mxp, Wkth, Wktl, bk, Khw, Klw);
  hipLaunchKernelGGL(k_proj_v, dim3(NB * NT), dim3(512), 0, stream,
                     myp, Wvth, Wvtl, bv, Vthw, Vtlw);
  hipLaunchKernelGGL(k_attn, dim3(NB * NT), dim3(512), 0, stream,
                     Qh, Ql, Khw, Klw, Vthw, Vtlw, Rw, Scw);
  hipLaunchKernelGGL(k_level2, dim3(NB * NI), dim3(64), 0, stream, Scw, Rw, out);
}

// Round 7
// 109.184 us; speedup vs baseline: 3.3256x; 1.4454x over previous
//
#include <hip/hip_runtime.h>
#include <hip/hip_bf16.h>

// Shapes (fixed)
#define NB 8
#define NT 64
#define NI 256
#define NJ 256
#define ND 256
#define NKD 64
#define NVD 64
#define SCL 0.125f   // 1/sqrt(64), both attention levels

typedef __attribute__((ext_vector_type(4))) float f32x4;
typedef __attribute__((ext_vector_type(8))) short bf16x8;  // 8 bf16 = 4 VGPR (MFMA A/B frag)
typedef __attribute__((ext_vector_type(4))) short bf16x4;  // 4 bf16 = 8 B packed store
typedef __attribute__((ext_vector_type(4))) unsigned int uint32x4;

// D[16 M][16 N] = A[16 M][32 K] * B[32 K][16 N] + C
// A frag: lane l holds A[l%16][8*(l/16)+e] ; B frag: B[8*(l/16)+e][l%16]
// C/D:    lane l holds D[4*(l/16)+r][l%16]
#define MFMA16(A, B, C) __builtin_amdgcn_mfma_f32_16x16x32_bf16((A), (B), (C), 0, 0, 0)

// LDS region bases (fused kernel): W hi 0 / W lo 32K ; K hi 64K / K lo 96K ; V hi 128K
#define WLO   32768
#define KBASE 65536
#define KLO   32768
#define VBASE 131072

__device__ __forceinline__ unsigned short f2bf(float x) {   // RNE
  return __builtin_bit_cast(unsigned short, __float2bfloat16(x));
}
__device__ __forceinline__ float bf2f(unsigned short h) {
  return __builtin_bit_cast(float, (unsigned)h << 16);
}
// split fp32 -> hi + lo bf16; hi+lo = x to ~2^-18 rel
__device__ __forceinline__ void split8(const float* __restrict__ x, bf16x8& hi, bf16x8& lo) {
  #pragma unroll
  for (int e = 0; e < 8; ++e) {
    unsigned short h = f2bf(x[e]);
    hi[e] = (short)h;
    lo[e] = (short)f2bf(x[e] - bf2f(h));
  }
}

// =====================================================================
// K0: pre-transpose + split weights:  W[256][64] -> Wt_hi/lo[64][256]
// =====================================================================
__global__ __launch_bounds__(256) void k_prep_wt(
    const float* __restrict__ Wk, const float* __restrict__ Wv,
    unsigned short* __restrict__ Wkth, unsigned short* __restrict__ Wktl,
    unsigned short* __restrict__ Wvth, unsigned short* __restrict__ Wvtl) {
  int t = blockIdx.x * 256 + threadIdx.x;   // 0..16383
  int d = t >> 6, kd = t & 63;
  float x = Wk[t];
  unsigned short h = f2bf(x);
  Wkth[kd * 256 + d] = h;
  Wktl[kd * 256 + d] = f2bf(x - bf2f(h));
  x = Wv[t];
  h = f2bf(x);
  Wvth[kd * 256 + d] = h;
  Wvtl[kd * 256 + d] = f2bf(x - bf2f(h));
}

// =====================================================================
// K1: Q = input_seq @ Wq + bq  (fp32 compute), output split bf16 hi/lo
// =====================================================================
__global__ __launch_bounds__(64) void k_proj_q(
    const float* __restrict__ x, const float* __restrict__ Wq,
    const float* __restrict__ bq,
    unsigned short* __restrict__ Qh, unsigned short* __restrict__ Ql) {
  int row = blockIdx.x, lane = threadIdx.x;
  __shared__ __align__(16) float xs[ND];
  const float* xr = x + (size_t)row * ND;
  #pragma unroll
  for (int cc = 0; cc < 4; ++cc) xs[lane + 64 * cc] = xr[lane + 64 * cc];
  __syncthreads();
  float acc = bq[lane];
  #pragma unroll 4
  for (int d = 0; d < ND; ++d) acc = fmaf(xs[d], Wq[d * NKD + lane], acc);
  unsigned short h = f2bf(acc);
  Qh[(size_t)row * NKD + lane] = h;
  Ql[(size_t)row * NKD + lane] = f2bf(acc - bf2f(h));
}

// =====================================================================
// W-plane staging into LDS [base, base+64K): hi plane at +0, lo at +32K.
// Plane row r (=kd) is 512 B = 32 16B-chunks, swizzle blk ^ (r&7).
// Fragment read: row mf*16+c, chunk ks*4+g -> blk (ks*4+g)^(r&7).
// =====================================================================
__device__ __forceinline__ void stage_w(
    char* wl, const unsigned short* __restrict__ Wth,
    const unsigned short* __restrict__ Wtl, int tid) {
  #pragma unroll
  for (int it = 0; it < 4; ++it) {
    int qq = tid + it * 512;            // 16B chunk id, 0..2047
    int r = qq >> 5, pb = qq & 31;
    uint4 vh = *(const uint4*)((const char*)Wth + (size_t)qq * 16);
    uint4 vl = *(const uint4*)((const char*)Wtl + (size_t)qq * 16);
    int dst = r * 512 + ((pb ^ (r & 7)) << 4);
    *(uint4*)(wl + dst) = vh;
    *(uint4*)(wl + WLO + dst) = vl;
  }
}

// =====================================================================
// K2: FUSED per-(b,t): K-proj -> LDS, V-proj -> LDS, attention.
// 512 thr (8 waves), grid 512, LDS 160 KB:
//   [0,64K)     W hi/lo (staged twice: Wk for phase A, Wv for phase B)
//   [64K,128K)  Kh[256 j][64 kd] + Kl   (16B-blk swizzle: blk ^ (j&7))
//   [128K,160K) Vh[64 vd][256 j]        (swizzle: blk ^ (vd&7))
// 4 barriers, each write-region -> reader handoff; after the last one
// LDS is read-only (in-register P redistribution) -> race-free.
// =====================================================================
__global__ __launch_bounds__(512) void k_fused(
    const float* __restrict__ Xm, const float* __restrict__ Ym,
    const unsigned short* __restrict__ Wkth, const unsigned short* __restrict__ Wktl,
    const unsigned short* __restrict__ Wvth, const unsigned short* __restrict__ Wvtl,
    const float* __restrict__ bk, const float* __restrict__ bv,
    const unsigned short* __restrict__ Qh, const unsigned short* __restrict__ Ql,
    unsigned short* __restrict__ R,      // [bt][256 i][64 vd] bf16
    float* __restrict__ Sc) {            // [bt][256 i] raw row max
  __shared__ __align__(16) char smemb[163840];   // 160 KB
  int tid = threadIdx.x;
  int bt = blockIdx.x, b = bt >> 6;
  int w = tid >> 6, lane = tid & 63, c = lane & 15, g = lane >> 4;

  // ---- stage Wk planes ----
  stage_w(smemb, Wkth, Wktl, tid);
  __syncthreads();

  // ---------------- Phase A: K-proj (swapped: M=kd, N=j) ----------------
  // wave w covers j = w*32 .. +32 (2 nf), kd full 64 (4 mf). prefetch-2.
  {
    const float* xr0 = Xm + (size_t)bt * 65536 + (size_t)(w * 32 + c) * 256 + g * 8;
    const float* xr1 = xr0 + 16 * 256;
    f32x4 acc[4][2];
    #pragma unroll
    for (int mf = 0; mf < 4; ++mf) { acc[mf][0] = (f32x4)0.f; acc[mf][1] = (f32x4)0.f; }
    float4 a00 = *(const float4*)(xr0),      a01 = *(const float4*)(xr0 + 4);
    float4 a10 = *(const float4*)(xr1),      a11 = *(const float4*)(xr1 + 4);
    float4 b00 = *(const float4*)(xr0 + 32), b01 = *(const float4*)(xr0 + 36);
    float4 b10 = *(const float4*)(xr1 + 32), b11 = *(const float4*)(xr1 + 36);
    #pragma unroll
    for (int ks = 0; ks < 8; ++ks) {
      float x0[8], x1[8];
      if (ks & 1) {
        *(float4*)&x0[0] = b00; *(float4*)&x0[4] = b01;
        *(float4*)&x1[0] = b10; *(float4*)&x1[4] = b11;
        if (ks < 6) {
          b00 = *(const float4*)(xr0 + (ks + 2) * 32);
          b01 = *(const float4*)(xr0 + (ks + 2) * 32 + 4);
          b10 = *(const float4*)(xr1 + (ks + 2) * 32);
          b11 = *(const float4*)(xr1 + (ks + 2) * 32 + 4);
        }
      } else {
        *(float4*)&x0[0] = a00; *(float4*)&x0[4] = a01;
        *(float4*)&x1[0] = a10; *(float4*)&x1[4] = a11;
        if (ks < 6) {
          a00 = *(const float4*)(xr0 + (ks + 2) * 32);
          a01 = *(const float4*)(xr0 + (ks + 2) * 32 + 4);
          a10 = *(const float4*)(xr1 + (ks + 2) * 32);
          a11 = *(const float4*)(xr1 + (ks + 2) * 32 + 4);
        }
      }
      bf16x8 b0h, b0l, b1h, b1l;
      split8(x0, b0h, b0l);
      split8(x1, b1h, b1l);
      #pragma unroll
      for (int mf = 0; mf < 4; ++mf) {
        int r = mf * 16 + c;
        int ba = r * 512 + (((ks * 4 + g) ^ (r & 7)) << 4);
        bf16x8 awh = *(const bf16x8*)(smemb + ba);
        bf16x8 awl = *(const bf16x8*)(smemb + WLO + ba);
        acc[mf][0] = MFMA16(awh, b0h, acc[mf][0]);
        acc[mf][0] = MFMA16(awl, b0h, acc[mf][0]);
        acc[mf][0] = MFMA16(awh, b0l, acc[mf][0]);
        acc[mf][1] = MFMA16(awh, b1h, acc[mf][1]);
        acc[mf][1] = MFMA16(awl, b1h, acc[mf][1]);
        acc[mf][1] = MFMA16(awh, b1l, acc[mf][1]);
      }
    }
    // write K hi/lo to LDS, attn layout: row j (128 B), blk ^ (j&7)
    #pragma unroll
    for (int nf = 0; nf < 2; ++nf) {
      int j = w * 32 + nf * 16 + c;
      #pragma unroll
      for (int mf = 0; mf < 4; ++mf) {   // element (kd = mf*16+4g+r, j)
        bf16x4 ph, pl4;
        #pragma unroll
        for (int r = 0; r < 4; ++r) {
          float v = acc[mf][nf][r] + bk[mf * 16 + g * 4 + r];
          unsigned short h = f2bf(v);
          ph[r] = (short)h;
          pl4[r] = (short)f2bf(v - bf2f(h));
        }
        int pb = mf * 2 + (g >> 1);
        int ba = KBASE + j * 128 + ((pb ^ (j & 7)) << 4) + (g & 1) * 8;
        *(bf16x4*)(smemb + ba) = ph;
        *(bf16x4*)(smemb + KLO + ba) = pl4;
      }
    }
  }
  __syncthreads();   // Wk reads + K writes complete

  // ---- stage Wv planes (overwrites Wk region) ----
  stage_w(smemb, Wvth, Wvtl, tid);
  __syncthreads();

  // ---------------- Phase B: V-proj (normal: M=j, N=vd) -----------------
  // wave w covers j = w*32 .. +32 (2 mf), vd full 64 (4 nf). prefetch-2.
  {
    const float* yr0 = Ym + (size_t)bt * 65536 + (size_t)(w * 32 + c) * 256 + g * 8;
    const float* yr1 = yr0 + 16 * 256;
    f32x4 acc[2][4];
    #pragma unroll
    for (int mf = 0; mf < 2; ++mf)
      #pragma unroll
      for (int nf = 0; nf < 4; ++nf) acc[mf][nf] = (f32x4)0.f;
    float4 a00 = *(const float4*)(yr0),      a01 = *(const float4*)(yr0 + 4);
    float4 a10 = *(const float4*)(yr1),      a11 = *(const float4*)(yr1 + 4);
    float4 b00 = *(const float4*)(yr0 + 32), b01 = *(const float4*)(yr0 + 36);
    float4 b10 = *(const float4*)(yr1 + 32), b11 = *(const float4*)(yr1 + 36);
    #pragma unroll
    for (int ks = 0; ks < 8; ++ks) {
      float y0[8], y1[8];
      if (ks & 1) {
        *(float4*)&y0[0] = b00; *(float4*)&y0[4] = b01;
        *(float4*)&y1[0] = b10; *(float4*)&y1[4] = b11;
        if (ks < 6) {
          b00 = *(const float4*)(yr0 + (ks + 2) * 32);
          b01 = *(const float4*)(yr0 + (ks + 2) * 32 + 4);
          b10 = *(const float4*)(yr1 + (ks + 2) * 32);
          b11 = *(const float4*)(yr1 + (ks + 2) * 32 + 4);
        }
      } else {
        *(float4*)&y0[0] = a00; *(float4*)&y0[4] = a01;
        *(float4*)&y1[0] = a10; *(float4*)&y1[4] = a11;
        if (ks < 6) {
          a00 = *(const float4*)(yr0 + (ks + 2) * 32);
          a01 = *(const float4*)(yr0 + (ks + 2) * 32 + 4);
          a10 = *(const float4*)(yr1 + (ks + 2) * 32);
          a11 = *(const float4*)(yr1 + (ks + 2) * 32 + 4);
        }
      }
      bf16x8 a0h, a0l, a1h, a1l;
      split8(y0, a0h, a0l);
      split8(y1, a1h, a1l);
      #pragma unroll
      for (int nf = 0; nf < 4; ++nf) {
        int r = nf * 16 + c;
        int ba = r * 512 + (((ks * 4 + g) ^ (r & 7)) << 4);
        bf16x8 bwh = *(const bf16x8*)(smemb + ba);
        bf16x8 bwl = *(const bf16x8*)(smemb + WLO + ba);
        acc[0][nf] = MFMA16(a0h, bwh, acc[0][nf]);
        acc[0][nf] = MFMA16(a0l, bwh, acc[0][nf]);
        acc[0][nf] = MFMA16(a0h, bwl, acc[0][nf]);
        acc[1][nf] = MFMA16(a1h, bwh, acc[1][nf]);
        acc[1][nf] = MFMA16(a1l, bwh, acc[1][nf]);
        acc[1][nf] = MFMA16(a1h, bwl, acc[1][nf]);
      }
    }
    // write V hi-only to LDS: row vd (512 B), blk ^ (vd&7)
    #pragma unroll
    for (int nf = 0; nf < 4; ++nf) {
      int vd = nf * 16 + c;
      float bs = bv[vd];
      #pragma unroll
      for (int mf = 0; mf < 2; ++mf) {   // element (j = w*32+mf*16+4g+r, vd)
        bf16x4 ph;
        #pragma unroll
        for (int r = 0; r < 4; ++r) ph[r] = (short)f2bf(acc[mf][nf][r] + bs);
        int pb = w * 4 + mf * 2 + (g >> 1);
        int ba = VBASE + vd * 512 + ((pb ^ (vd & 7)) << 4) + (g & 1) * 8;
        *(bf16x4*)(smemb + ba) = ph;
      }
    }
  }
  __syncthreads();   // the LAST barrier: LDS read-only from here on

  // ---------------- Phase C: attention (wave w: i = w*32 .. +32) --------
  #pragma unroll
  for (int ic = 0; ic < 2; ++ic) {
    int i = w * 32 + ic * 16 + c;
    bf16x8 qbh[2], qbl[2];
    #pragma unroll
    for (int ks = 0; ks < 2; ++ks) {
      size_t qo = ((size_t)b * NI + i) * NKD + ks * 32 + g * 8;
      qbh[ks] = *(const bf16x8*)(Qh + qo);
      qbl[ks] = *(const bf16x8*)(Ql + qo);
    }

    // S^T = K * Q^T : sa[jf] holds S^T[j = 16jf+4g+r][i]
    f32x4 sa[16];
    #pragma unroll
    for (int jf = 0; jf < 16; ++jf) sa[jf] = (f32x4)0.f;
    #pragma unroll
    for (int jf = 0; jf < 16; ++jf) {
      int j = jf * 16 + c;
      #pragma unroll
      for (int ks = 0; ks < 2; ++ks) {
        int ba = KBASE + j * 128 + (((ks * 4 + g) ^ (j & 7)) << 4);
        bf16x8 kh = *(const bf16x8*)(smemb + ba);
        bf16x8 kl = *(const bf16x8*)(smemb + KLO + ba);
        sa[jf] = MFMA16(kh, qbh[ks], sa[jf]);
        sa[jf] = MFMA16(kl, qbh[ks], sa[jf]);
        sa[jf] = MFMA16(kh, qbl[ks], sa[jf]);
      }
    }

    // softmax over j (lane-local + 2 shfl)
    float mx = sa[0][0];
    #pragma unroll
    for (int jf = 0; jf < 16; ++jf)
      #pragma unroll
      for (int r = 0; r < 4; ++r) mx = fmaxf(mx, sa[jf][r]);
    mx = fmaxf(mx, __shfl_xor(mx, 16));
    mx = fmaxf(mx, __shfl_xor(mx, 32));
    if (g == 0) Sc[(size_t)bt * NI + i] = mx;   // raw max
    float sum = 0.f;
    #pragma unroll
    for (int jf = 0; jf < 16; ++jf)
      #pragma unroll
      for (int r = 0; r < 4; ++r) {
        float p = __expf((sa[jf][r] - mx) * SCL);
        sa[jf][r] = p;
        sum += p;
      }
    sum += __shfl_xor(sum, 16);
    sum += __shfl_xor(sum, 32);
    float linv = 1.0f / sum;

    // pack P into bf16-pair words: plo/phi[jf] = j {16jf+4g+0,1}/{2,3}
    unsigned int plo[16], phi[16];
    #pragma unroll
    for (int jf = 0; jf < 16; ++jf) {
      plo[jf] = (unsigned int)f2bf(sa[jf][0]) | ((unsigned int)f2bf(sa[jf][1]) << 16);
      phi[jf] = (unsigned int)f2bf(sa[jf][2]) | ((unsigned int)f2bf(sa[jf][3]) << 16);
    }

    // in-register P^T redistribution (verified R4/R6)
    int srcA = c + 32 * (g & 1);
    int srcB = srcA + 16;
    bool hiH = (g >= 2);

    f32x4 racc[4];
    #pragma unroll
    for (int vf = 0; vf < 4; ++vf) racc[vf] = (f32x4)0.f;
    #pragma unroll
    for (int js = 0; js < 8; ++js) {
      int a0 = __shfl((int)plo[2 * js], srcA);
      int a1 = __shfl((int)phi[2 * js], srcA);
      int a2 = __shfl((int)plo[2 * js], srcB);
      int a3 = __shfl((int)phi[2 * js], srcB);
      int b0 = __shfl((int)plo[2 * js + 1], srcA);
      int b1 = __shfl((int)phi[2 * js + 1], srcA);
      int b2 = __shfl((int)plo[2 * js + 1], srcB);
      int b3 = __shfl((int)phi[2 * js + 1], srcB);
      uint32x4 pw;
      pw[0] = (unsigned int)(hiH ? b0 : a0);
      pw[1] = (unsigned int)(hiH ? b1 : a1);
      pw[2] = (unsigned int)(hiH ? b2 : a2);
      pw[3] = (unsigned int)(hiH ? b3 : a3);
      bf16x8 pf = __builtin_bit_cast(bf16x8, pw);
      #pragma unroll
      for (int vf = 0; vf < 4; ++vf) {
        int vd = vf * 16 + c;
        int vba = VBASE + vd * 512 + (((js * 4 + g) ^ (vd & 7)) << 4);
        bf16x8 vh = *(const bf16x8*)(smemb + vba);
        racc[vf] = MFMA16(vh, pf, racc[vf]);
      }
    }

    // write R[bt][i][vd] bf16, normalized; element (vd = vf*16+4g+r, i)
    #pragma unroll
    for (int vf = 0; vf < 4; ++vf) {
      bf16x4 rk;
      #pragma unroll
      for (int r = 0; r < 4; ++r) rk[r] = (short)f2bf(racc[vf][r] * linv);
      *(bf16x4*)(R + ((size_t)bt * NI + i) * NKD + vf * 16 + g * 4) = rk;
    }
  }
}

// =====================================================================
// K3: level-2 attention over t. grid = NB*NI, 64 thr. lane = t then vd.
// =====================================================================
__global__ __launch_bounds__(64) void k_level2(
    const float* __restrict__ Sc,         // [bt][256]
    const unsigned short* __restrict__ R, // [bt][256][64] bf16
    float* __restrict__ out) {            // [b][256][64] f32
  int bi = blockIdx.x;
  int b = bi >> 8, i = bi & 255;
  int lane = threadIdx.x;
  float sc = Sc[((size_t)b * NT + lane) * NI + i];
  float mx = sc;
  #pragma unroll
  for (int off = 32; off; off >>= 1) mx = fmaxf(mx, __shfl_xor(mx, off));
  float e = __expf((sc - mx) * SCL);
  float sum = e;
  #pragma unroll
  for (int off = 32; off; off >>= 1) sum += __shfl_xor(sum, off);
  float wn = e / sum;
  float acc = 0.f;
  for (int t = 0; t < NT; ++t) {
    float wt = __shfl(wn, t);
    acc = fmaf(wt, bf2f(R[(((size_t)b * NT + t) * NI + i) * NKD + lane]), acc);
  }
  out[((size_t)b * NI + i) * NVD + lane] = acc;
}

// =====================================================================
extern "C" void kernel_launch(void* const* d_in, const int* in_sizes, int n_in,
                              void* d_out, int out_size, void* d_ws, size_t ws_size,
                              hipStream_t stream) {
  const float* x   = (const float*)d_in[0];
  const float* mxp = (const float*)d_in[1];
  const float* myp = (const float*)d_in[2];
  const float* Wq  = (const float*)d_in[3];
  const float* bq  = (const float*)d_in[4];
  const float* Wk  = (const float*)d_in[5];
  const float* bk  = (const float*)d_in[6];
  const float* Wv  = (const float*)d_in[7];
  const float* bv  = (const float*)d_in[8];
  float* out = (float*)d_out;

  // workspace carve (~18 MB)
  char* p = (char*)d_ws;
  auto alloc = [&](size_t bytes) { char* r = p; p += (bytes + 255) & ~(size_t)255; return r; };
  unsigned short* Qh   = (unsigned short*)alloc(2048 * 64 * 2);
  unsigned short* Ql   = (unsigned short*)alloc(2048 * 64 * 2);
  unsigned short* Rw   = (unsigned short*)alloc((size_t)131072 * 64 * 2);
  float*          Scw  = (float*)alloc((size_t)131072 * 4);
  unsigned short* Wkth = (unsigned short*)alloc(64 * 256 * 2);
  unsigned short* Wktl = (unsigned short*)alloc(64 * 256 * 2);
  unsigned short* Wvth = (unsigned short*)alloc(64 * 256 * 2);
  unsigned short* Wvtl = (unsigned short*)alloc(64 * 256 * 2);

  hipLaunchKernelGGL(k_prep_wt, dim3(64), dim3(256), 0, stream,
                     Wk, Wv, Wkth, Wktl, Wvth, Wvtl);
  hipLaunchKernelGGL(k_proj_q, dim3(NB * NI), dim3(64), 0, stream, x, Wq, bq, Qh, Ql);
  hipLaunchKernelGGL(k_fused, dim3(NB * NT), dim3(512), 0, stream,
                     mxp, myp, Wkth, Wktl, Wvth, Wvtl, bk, bv, Qh, Ql, Rw, Scw);
  hipLaunchKernelGGL(k_level2, dim3(NB * NI), dim3(64), 0, stream, Scw, Rw, out);
}

// Round 8
// 98.807 us; speedup vs baseline: 3.6748x; 1.1050x over previous
//
#include <hip/hip_runtime.h>
#include <hip/hip_bf16.h>

// Shapes (fixed)
#define NB 8
#define NT 64
#define NI 256
#define NJ 256
#define ND 256
#define NKD 64
#define NVD 64
#define SCL 0.125f   // 1/sqrt(64), both attention levels

typedef __attribute__((ext_vector_type(4))) float f32x4;
typedef __attribute__((ext_vector_type(8))) short bf16x8;  // 8 bf16 = 4 VGPR (MFMA A/B frag)
typedef __attribute__((ext_vector_type(4))) short bf16x4;  // 4 bf16 = 8 B packed store
typedef __attribute__((ext_vector_type(4))) unsigned int uint32x4;

// D[16 M][16 N] = A[16 M][32 K] * B[32 K][16 N] + C
// A frag: lane l holds A[l%16][8*(l/16)+e] ; B frag: B[8*(l/16)+e][l%16]
// C/D:    lane l holds D[4*(l/16)+r][l%16]
#define MFMA16(A, B, C) __builtin_amdgcn_mfma_f32_16x16x32_bf16((A), (B), (C), 0, 0, 0)

// LDS overlay (64 KB total):
//   R1 [0,32K):    Wv-hi  -> Wk-hi -> K-hi[256 j][64 kd] (rows 128 B, blk^(j&7))
//   R2 [32K,64K):  Wv-lo  -> V-hi[64 vd][256 j]          (rows 512 B, blk^(vd&7))
#define R2B 32768

__device__ __forceinline__ unsigned short f2bf(float x) {   // RNE
  return __builtin_bit_cast(unsigned short, __float2bfloat16(x));
}
__device__ __forceinline__ float bf2f(unsigned short h) {
  return __builtin_bit_cast(float, (unsigned)h << 16);
}
// split fp32 -> hi + lo bf16; hi+lo = x to ~2^-18 rel
__device__ __forceinline__ void split8(const float* __restrict__ x, bf16x8& hi, bf16x8& lo) {
  #pragma unroll
  for (int e = 0; e < 8; ++e) {
    unsigned short h = f2bf(x[e]);
    hi[e] = (short)h;
    lo[e] = (short)f2bf(x[e] - bf2f(h));
  }
}

// =====================================================================
// K0: pre-transpose + split weights:  W[256][64] -> Wt_hi/lo[64][256]
// =====================================================================
__global__ __launch_bounds__(256) void k_prep_wt(
    const float* __restrict__ Wk, const float* __restrict__ Wv,
    unsigned short* __restrict__ Wkth,
    unsigned short* __restrict__ Wvth, unsigned short* __restrict__ Wvtl) {
  int t = blockIdx.x * 256 + threadIdx.x;   // 0..16383
  int d = t >> 6, kd = t & 63;
  Wkth[kd * 256 + d] = f2bf(Wk[t]);         // K path: hi plane only (2-term)
  float x = Wv[t];
  unsigned short h = f2bf(x);
  Wvth[kd * 256 + d] = h;
  Wvtl[kd * 256 + d] = f2bf(x - bf2f(h));
}

// =====================================================================
// K1: Q = input_seq @ Wq + bq  (fp32 compute), output split bf16 hi/lo
// =====================================================================
__global__ __launch_bounds__(64) void k_proj_q(
    const float* __restrict__ x, const float* __restrict__ Wq,
    const float* __restrict__ bq,
    unsigned short* __restrict__ Qh, unsigned short* __restrict__ Ql) {
  int row = blockIdx.x, lane = threadIdx.x;
  __shared__ __align__(16) float xs[ND];
  const float* xr = x + (size_t)row * ND;
  #pragma unroll
  for (int cc = 0; cc < 4; ++cc) xs[lane + 64 * cc] = xr[lane + 64 * cc];
  __syncthreads();
  float acc = bq[lane];
  #pragma unroll 4
  for (int d = 0; d < ND; ++d) acc = fmaf(xs[d], Wq[d * NKD + lane], acc);
  unsigned short h = f2bf(acc);
  Qh[(size_t)row * NKD + lane] = h;
  Ql[(size_t)row * NKD + lane] = f2bf(acc - bf2f(h));
}

// =====================================================================
// Single W-plane staging: row r (=kd) is 512 B = 32 16B-chunks,
// swizzle blk ^ (r&7). Fragment read: row f*16+c, chunk ks*4+g.
// =====================================================================
__device__ __forceinline__ void stage_plane(
    char* dstb, const unsigned short* __restrict__ Wt, int tid) {
  #pragma unroll
  for (int it = 0; it < 4; ++it) {
    int qq = tid + it * 512;            // 16B chunk id, 0..2047
    int r = qq >> 5, pb = qq & 31;
    uint4 v = *(const uint4*)((const char*)Wt + (size_t)qq * 16);
    *(uint4*)(dstb + r * 512 + ((pb ^ (r & 7)) << 4)) = v;
  }
}

// =====================================================================
// K2: FUSED per-(b,t), 64 KB LDS, 512 thr (8 waves), grid 512.
// 2 blocks/CU resident (4 waves/SIMD) — block n+1 memory phases
// overlap block n compute. Order: V-proj (3-term), K-proj (2-term),
// attention (S 2-term, PV 1-term). 5 barriers; after the last one LDS
// is read-only (in-register P redistribution) -> race-free.
// =====================================================================
__global__ __launch_bounds__(512, 4) void k_fused(
    const float* __restrict__ Xm, const float* __restrict__ Ym,
    const unsigned short* __restrict__ Wkth,
    const unsigned short* __restrict__ Wvth, const unsigned short* __restrict__ Wvtl,
    const float* __restrict__ bk, const float* __restrict__ bv,
    const unsigned short* __restrict__ Qh, const unsigned short* __restrict__ Ql,
    unsigned short* __restrict__ R,      // [bt][256 i][64 vd] bf16
    float* __restrict__ Sc) {            // [bt][256 i] raw row max
  __shared__ __align__(16) char smemb[65536];   // 64 KB
  int tid = threadIdx.x;
  int bt = blockIdx.x, b = bt >> 6;
  int w = tid >> 6, lane = tid & 63, c = lane & 15, g = lane >> 4;

  // ---- stage Wv hi -> R1, Wv lo -> R2 ----
  stage_plane(smemb, Wvth, tid);
  stage_plane(smemb + R2B, Wvtl, tid);
  __syncthreads();                                   // barrier 1

  // ---------------- Phase B: V-proj (normal: M=j, N=vd), 3-term --------
  // wave w covers j = w*32 .. +32 (2 mf), vd full 64 (4 nf). prefetch-2.
  f32x4 vacc[2][4];
  {
    const float* yr0 = Ym + (size_t)bt * 65536 + (size_t)(w * 32 + c) * 256 + g * 8;
    const float* yr1 = yr0 + 16 * 256;
    #pragma unroll
    for (int mf = 0; mf < 2; ++mf)
      #pragma unroll
      for (int nf = 0; nf < 4; ++nf) vacc[mf][nf] = (f32x4)0.f;
    float4 a00 = *(const float4*)(yr0),      a01 = *(const float4*)(yr0 + 4);
    float4 a10 = *(const float4*)(yr1),      a11 = *(const float4*)(yr1 + 4);
    float4 b00 = *(const float4*)(yr0 + 32), b01 = *(const float4*)(yr0 + 36);
    float4 b10 = *(const float4*)(yr1 + 32), b11 = *(const float4*)(yr1 + 36);
    #pragma unroll
    for (int ks = 0; ks < 8; ++ks) {
      float y0[8], y1[8];
      if (ks & 1) {
        *(float4*)&y0[0] = b00; *(float4*)&y0[4] = b01;
        *(float4*)&y1[0] = b10; *(float4*)&y1[4] = b11;
        if (ks < 6) {
          b00 = *(const float4*)(yr0 + (ks + 2) * 32);
          b01 = *(const float4*)(yr0 + (ks + 2) * 32 + 4);
          b10 = *(const float4*)(yr1 + (ks + 2) * 32);
          b11 = *(const float4*)(yr1 + (ks + 2) * 32 + 4);
        }
      } else {
        *(float4*)&y0[0] = a00; *(float4*)&y0[4] = a01;
        *(float4*)&y1[0] = a10; *(float4*)&y1[4] = a11;
        if (ks < 6) {
          a00 = *(const float4*)(yr0 + (ks + 2) * 32);
          a01 = *(const float4*)(yr0 + (ks + 2) * 32 + 4);
          a10 = *(const float4*)(yr1 + (ks + 2) * 32);
          a11 = *(const float4*)(yr1 + (ks + 2) * 32 + 4);
        }
      }
      bf16x8 a0h, a0l, a1h, a1l;
      split8(y0, a0h, a0l);
      split8(y1, a1h, a1l);
      #pragma unroll
      for (int nf = 0; nf < 4; ++nf) {
        int r = nf * 16 + c;
        int ba = r * 512 + (((ks * 4 + g) ^ (r & 7)) << 4);
        bf16x8 bwh = *(const bf16x8*)(smemb + ba);
        bf16x8 bwl = *(const bf16x8*)(smemb + R2B + ba);
        vacc[0][nf] = MFMA16(a0h, bwh, vacc[0][nf]);
        vacc[0][nf] = MFMA16(a0l, bwh, vacc[0][nf]);
        vacc[0][nf] = MFMA16(a0h, bwl, vacc[0][nf]);
        vacc[1][nf] = MFMA16(a1h, bwh, vacc[1][nf]);
        vacc[1][nf] = MFMA16(a1l, bwh, vacc[1][nf]);
        vacc[1][nf] = MFMA16(a1h, bwl, vacc[1][nf]);
      }
    }
  }
  __syncthreads();                                   // barrier 2 (Wv reads done)

  // ---- epilogue V: write V-hi -> R2 (over Wv-lo); stage Wk-hi -> R1 ----
  #pragma unroll
  for (int nf = 0; nf < 4; ++nf) {
    int vd = nf * 16 + c;
    float bs = bv[vd];
    #pragma unroll
    for (int mf = 0; mf < 2; ++mf) {   // element (j = w*32+mf*16+4g+r, vd)
      bf16x4 ph;
      #pragma unroll
      for (int r = 0; r < 4; ++r) ph[r] = (short)f2bf(vacc[mf][nf][r] + bs);
      int pb = w * 4 + mf * 2 + (g >> 1);
      int ba = R2B + vd * 512 + ((pb ^ (vd & 7)) << 4) + (g & 1) * 8;
      *(bf16x4*)(smemb + ba) = ph;
    }
  }
  stage_plane(smemb, Wkth, tid);
  __syncthreads();                                   // barrier 3

  // ---------------- Phase A: K-proj (swapped: M=kd, N=j), 2-term --------
  // wave w covers j = w*32 .. +32 (2 nf), kd full 64 (4 mf). prefetch-2.
  f32x4 kacc[4][2];
  {
    const float* xr0 = Xm + (size_t)bt * 65536 + (size_t)(w * 32 + c) * 256 + g * 8;
    const float* xr1 = xr0 + 16 * 256;
    #pragma unroll
    for (int mf = 0; mf < 4; ++mf) { kacc[mf][0] = (f32x4)0.f; kacc[mf][1] = (f32x4)0.f; }
    float4 a00 = *(const float4*)(xr0),      a01 = *(const float4*)(xr0 + 4);
    float4 a10 = *(const float4*)(xr1),      a11 = *(const float4*)(xr1 + 4);
    float4 b00 = *(const float4*)(xr0 + 32), b01 = *(const float4*)(xr0 + 36);
    float4 b10 = *(const float4*)(xr1 + 32), b11 = *(const float4*)(xr1 + 36);
    #pragma unroll
    for (int ks = 0; ks < 8; ++ks) {
      float x0[8], x1[8];
      if (ks & 1) {
        *(float4*)&x0[0] = b00; *(float4*)&x0[4] = b01;
        *(float4*)&x1[0] = b10; *(float4*)&x1[4] = b11;
        if (ks < 6) {
          b00 = *(const float4*)(xr0 + (ks + 2) * 32);
          b01 = *(const float4*)(xr0 + (ks + 2) * 32 + 4);
          b10 = *(const float4*)(xr1 + (ks + 2) * 32);
          b11 = *(const float4*)(xr1 + (ks + 2) * 32 + 4);
        }
      } else {
        *(float4*)&x0[0] = a00; *(float4*)&x0[4] = a01;
        *(float4*)&x1[0] = a10; *(float4*)&x1[4] = a11;
        if (ks < 6) {
          a00 = *(const float4*)(xr0 + (ks + 2) * 32);
          a01 = *(const float4*)(xr0 + (ks + 2) * 32 + 4);
          a10 = *(const float4*)(xr1 + (ks + 2) * 32);
          a11 = *(const float4*)(xr1 + (ks + 2) * 32 + 4);
        }
      }
      bf16x8 b0h, b0l, b1h, b1l;
      split8(x0, b0h, b0l);
      split8(x1, b1h, b1l);
      #pragma unroll
      for (int mf = 0; mf < 4; ++mf) {
        int r = mf * 16 + c;
        int ba = r * 512 + (((ks * 4 + g) ^ (r & 7)) << 4);
        bf16x8 awh = *(const bf16x8*)(smemb + ba);
        kacc[mf][0] = MFMA16(awh, b0h, kacc[mf][0]);
        kacc[mf][0] = MFMA16(awh, b0l, kacc[mf][0]);
        kacc[mf][1] = MFMA16(awh, b1h, kacc[mf][1]);
        kacc[mf][1] = MFMA16(awh, b1l, kacc[mf][1]);
      }
    }
  }
  __syncthreads();                                   // barrier 4 (Wk reads done)

  // ---- epilogue K: write K-hi -> R1 (over Wk-hi) ----
  #pragma unroll
  for (int nf = 0; nf < 2; ++nf) {
    int j = w * 32 + nf * 16 + c;
    #pragma unroll
    for (int mf = 0; mf < 4; ++mf) {   // element (kd = mf*16+4g+r, j)
      bf16x4 ph;
      #pragma unroll
      for (int r = 0; r < 4; ++r)
        ph[r] = (short)f2bf(kacc[mf][nf][r] + bk[mf * 16 + g * 4 + r]);
      int pb = mf * 2 + (g >> 1);
      int ba = j * 128 + ((pb ^ (j & 7)) << 4) + (g & 1) * 8;
      *(bf16x4*)(smemb + ba) = ph;
    }
  }
  __syncthreads();                                   // barrier 5: LDS read-only now

  // ---------------- Phase C: attention (wave w: i = w*32 .. +32) --------
  #pragma unroll
  for (int ic = 0; ic < 2; ++ic) {
    int i = w * 32 + ic * 16 + c;
    bf16x8 qbh[2], qbl[2];
    #pragma unroll
    for (int ks = 0; ks < 2; ++ks) {
      size_t qo = ((size_t)b * NI + i) * NKD + ks * 32 + g * 8;
      qbh[ks] = *(const bf16x8*)(Qh + qo);
      qbl[ks] = *(const bf16x8*)(Ql + qo);
    }

    // S^T = K * Q^T (2-term): sa[jf] holds S^T[j = 16jf+4g+r][i]
    f32x4 sa[16];
    #pragma unroll
    for (int jf = 0; jf < 16; ++jf) sa[jf] = (f32x4)0.f;
    #pragma unroll
    for (int jf = 0; jf < 16; ++jf) {
      int j = jf * 16 + c;
      #pragma unroll
      for (int ks = 0; ks < 2; ++ks) {
        int ba = j * 128 + (((ks * 4 + g) ^ (j & 7)) << 4);
        bf16x8 kh = *(const bf16x8*)(smemb + ba);
        sa[jf] = MFMA16(kh, qbh[ks], sa[jf]);
        sa[jf] = MFMA16(kh, qbl[ks], sa[jf]);
      }
    }

    // softmax over j (lane-local + 2 shfl)
    float mx = sa[0][0];
    #pragma unroll
    for (int jf = 0; jf < 16; ++jf)
      #pragma unroll
      for (int r = 0; r < 4; ++r) mx = fmaxf(mx, sa[jf][r]);
    mx = fmaxf(mx, __shfl_xor(mx, 16));
    mx = fmaxf(mx, __shfl_xor(mx, 32));
    if (g == 0) Sc[(size_t)bt * NI + i] = mx;   // raw max
    float sum = 0.f;
    #pragma unroll
    for (int jf = 0; jf < 16; ++jf)
      #pragma unroll
      for (int r = 0; r < 4; ++r) {
        float p = __expf((sa[jf][r] - mx) * SCL);
        sa[jf][r] = p;
        sum += p;
      }
    sum += __shfl_xor(sum, 16);
    sum += __shfl_xor(sum, 32);
    float linv = 1.0f / sum;

    // pack P into bf16-pair words: plo/phi[jf] = j {16jf+4g+0,1}/{2,3}
    unsigned int plo[16], phi[16];
    #pragma unroll
    for (int jf = 0; jf < 16; ++jf) {
      plo[jf] = (unsigned int)f2bf(sa[jf][0]) | ((unsigned int)f2bf(sa[jf][1]) << 16);
      phi[jf] = (unsigned int)f2bf(sa[jf][2]) | ((unsigned int)f2bf(sa[jf][3]) << 16);
    }

    // in-register P^T redistribution (verified R4/R6/R7)
    int srcA = c + 32 * (g & 1);
    int srcB = srcA + 16;
    bool hiH = (g >= 2);

    f32x4 racc[4];
    #pragma unroll
    for (int vf = 0; vf < 4; ++vf) racc[vf] = (f32x4)0.f;
    #pragma unroll
    for (int js = 0; js < 8; ++js) {
      int a0 = __shfl((int)plo[2 * js], srcA);
      int a1 = __shfl((int)phi[2 * js], srcA);
      int a2 = __shfl((int)plo[2 * js], srcB);
      int a3 = __shfl((int)phi[2 * js], srcB);
      int b0 = __shfl((int)plo[2 * js + 1], srcA);
      int b1 = __shfl((int)phi[2 * js + 1], srcA);
      int b2 = __shfl((int)plo[2 * js + 1], srcB);
      int b3 = __shfl((int)phi[2 * js + 1], srcB);
      uint32x4 pw;
      pw[0] = (unsigned int)(hiH ? b0 : a0);
      pw[1] = (unsigned int)(hiH ? b1 : a1);
      pw[2] = (unsigned int)(hiH ? b2 : a2);
      pw[3] = (unsigned int)(hiH ? b3 : a3);
      bf16x8 pf = __builtin_bit_cast(bf16x8, pw);
      #pragma unroll
      for (int vf = 0; vf < 4; ++vf) {
        int vd = vf * 16 + c;
        int vba = R2B + vd * 512 + (((js * 4 + g) ^ (vd & 7)) << 4);
        bf16x8 vh = *(const bf16x8*)(smemb + vba);
        racc[vf] = MFMA16(vh, pf, racc[vf]);
      }
    }

    // write R[bt][i][vd] bf16, normalized; element (vd = vf*16+4g+r, i)
    #pragma unroll
    for (int vf = 0; vf < 4; ++vf) {
      bf16x4 rk;
      #pragma unroll
      for (int r = 0; r < 4; ++r) rk[r] = (short)f2bf(racc[vf][r] * linv);
      *(bf16x4*)(R + ((size_t)bt * NI + i) * NKD + vf * 16 + g * 4) = rk;
    }
  }
}

// =====================================================================
// K3: level-2 attention over t. grid = NB*NI, 64 thr. lane = t then vd.
// =====================================================================
__global__ __launch_bounds__(64) void k_level2(
    const float* __restrict__ Sc,         // [bt][256]
    const unsigned short* __restrict__ R, // [bt][256][64] bf16
    float* __restrict__ out) {            // [b][256][64] f32
  int bi = blockIdx.x;
  int b = bi >> 8, i = bi & 255;
  int lane = threadIdx.x;
  float sc = Sc[((size_t)b * NT + lane) * NI + i];
  float mx = sc;
  #pragma unroll
  for (int off = 32; off; off >>= 1) mx = fmaxf(mx, __shfl_xor(mx, off));
  float e = __expf((sc - mx) * SCL);
  float sum = e;
  #pragma unroll
  for (int off = 32; off; off >>= 1) sum += __shfl_xor(sum, off);
  float wn = e / sum;
  float acc = 0.f;
  for (int t = 0; t < NT; ++t) {
    float wt = __shfl(wn, t);
    acc = fmaf(wt, bf2f(R[(((size_t)b * NT + t) * NI + i) * NKD + lane]), acc);
  }
  out[((size_t)b * NI + i) * NVD + lane] = acc;
}

// =====================================================================
extern "C" void kernel_launch(void* const* d_in, const int* in_sizes, int n_in,
                              void* d_out, int out_size, void* d_ws, size_t ws_size,
                              hipStream_t stream) {
  const float* x   = (const float*)d_in[0];
  const float* mxp = (const float*)d_in[1];
  const float* myp = (const float*)d_in[2];
  const float* Wq  = (const float*)d_in[3];
  const float* bq  = (const float*)d_in[4];
  const float* Wk  = (const float*)d_in[5];
  const float* bk  = (const float*)d_in[6];
  const float* Wv  = (const float*)d_in[7];
  const float* bv  = (const float*)d_in[8];
  float* out = (float*)d_out;

  // workspace carve (~18 MB)
  char* p = (char*)d_ws;
  auto alloc = [&](size_t bytes) { char* r = p; p += (bytes + 255) & ~(size_t)255; return r; };
  unsigned short* Qh   = (unsigned short*)alloc(2048 * 64 * 2);
  unsigned short* Ql   = (unsigned short*)alloc(2048 * 64 * 2);
  unsigned short* Rw   = (unsigned short*)alloc((size_t)131072 * 64 * 2);
  float*          Scw  = (float*)alloc((size_t)131072 * 4);
  unsigned short* Wkth = (unsigned short*)alloc(64 * 256 * 2);
  unsigned short* Wvth = (unsigned short*)alloc(64 * 256 * 2);
  unsigned short* Wvtl = (unsigned short*)alloc(64 * 256 * 2);

  hipLaunchKernelGGL(k_prep_wt, dim3(64), dim3(256), 0, stream,
                     Wk, Wv, Wkth, Wvth, Wvtl);
  hipLaunchKernelGGL(k_proj_q, dim3(NB * NI), dim3(64), 0, stream, x, Wq, bq, Qh, Ql);
  hipLaunchKernelGGL(k_fused, dim3(NB * NT), dim3(512), 0, stream,
                     mxp, myp, Wkth, Wvth, Wvtl, bk, bv, Qh, Ql, Rw, Scw);
  hipLaunchKernelGGL(k_level2, dim3(NB * NI), dim3(64), 0, stream, Scw, Rw, out);
}

// Round 9
// 96.588 us; speedup vs baseline: 3.7593x; 1.0230x over previous
//
#include <hip/hip_runtime.h>
#include <hip/hip_bf16.h>

// Shapes (fixed)
#define NB 8
#define NT 64
#define NI 256
#define NJ 256
#define ND 256
#define NKD 64
#define NVD 64
#define SCL 0.125f   // 1/sqrt(64), both attention levels

typedef __attribute__((ext_vector_type(4))) float f32x4;
typedef __attribute__((ext_vector_type(8))) short bf16x8;  // 8 bf16 = 4 VGPR (MFMA A/B frag)
typedef __attribute__((ext_vector_type(4))) short bf16x4;  // 4 bf16 = 8 B packed store
typedef __attribute__((ext_vector_type(4))) unsigned int uint32x4;

// D[16 M][16 N] = A[16 M][32 K] * B[32 K][16 N] + C
// A frag: lane l holds A[l%16][8*(l/16)+e] ; B frag: B[8*(l/16)+e][l%16]
// C/D:    lane l holds D[4*(l/16)+r][l%16]
#define MFMA16(A, B, C) __builtin_amdgcn_mfma_f32_16x16x32_bf16((A), (B), (C), 0, 0, 0)

// LDS overlay (64 KB total):
//   R1 [0,32K):    Wv-hi  -> Wk-hi -> K-hi[256 j][64 kd] (rows 128 B, blk^(j&7))
//   R2 [32K,64K):  Wv-lo  -> V-hi[64 vd][256 j]          (rows 512 B, blk^(vd&7))
#define R2B 32768

__device__ __forceinline__ unsigned short f2bf(float x) {   // RNE
  return __builtin_bit_cast(unsigned short, __float2bfloat16(x));
}
__device__ __forceinline__ float bf2f(unsigned short h) {
  return __builtin_bit_cast(float, (unsigned)h << 16);
}
// split fp32 -> hi + lo bf16; hi+lo = x to ~2^-18 rel
__device__ __forceinline__ void split8(const float* __restrict__ x, bf16x8& hi, bf16x8& lo) {
  #pragma unroll
  for (int e = 0; e < 8; ++e) {
    unsigned short h = f2bf(x[e]);
    hi[e] = (short)h;
    lo[e] = (short)f2bf(x[e] - bf2f(h));
  }
}

// =====================================================================
// K1: merged prep (blocks 0..255) + Q-proj (blocks 256..2303), 64 thr.
//  prep: W[256][64] -> Wt planes (Wk hi only; Wv hi+lo)
//  Q-proj: Q = input_seq @ Wq + bq (fp32), output split bf16 hi/lo
// =====================================================================
__global__ __launch_bounds__(64) void k_prep_projq(
    const float* __restrict__ x, const float* __restrict__ Wq,
    const float* __restrict__ bq,
    const float* __restrict__ Wk, const float* __restrict__ Wv,
    unsigned short* __restrict__ Wkth,
    unsigned short* __restrict__ Wvth, unsigned short* __restrict__ Wvtl,
    unsigned short* __restrict__ Qh, unsigned short* __restrict__ Ql) {
  int lane = threadIdx.x;
  if (blockIdx.x < 256) {               // prep weights
    int t = blockIdx.x * 64 + lane;     // 0..16383
    int d = t >> 6, kd = t & 63;
    Wkth[kd * 256 + d] = f2bf(Wk[t]);
    float v = Wv[t];
    unsigned short h = f2bf(v);
    Wvth[kd * 256 + d] = h;
    Wvtl[kd * 256 + d] = f2bf(v - bf2f(h));
    return;
  }
  int row = blockIdx.x - 256;
  __shared__ __align__(16) float xs[ND];
  const float* xr = x + (size_t)row * ND;
  #pragma unroll
  for (int cc = 0; cc < 4; ++cc) xs[lane + 64 * cc] = xr[lane + 64 * cc];
  __syncthreads();
  float acc = bq[lane];
  #pragma unroll 4
  for (int d = 0; d < ND; ++d) acc = fmaf(xs[d], Wq[d * NKD + lane], acc);
  unsigned short h = f2bf(acc);
  Qh[(size_t)row * NKD + lane] = h;
  Ql[(size_t)row * NKD + lane] = f2bf(acc - bf2f(h));
}

// =====================================================================
// Single W-plane staging: row r (=kd) is 512 B = 32 16B-chunks,
// swizzle blk ^ (r&7). Fragment read: row f*16+c, chunk ks*4+g.
// =====================================================================
__device__ __forceinline__ void stage_plane(
    char* dstb, const unsigned short* __restrict__ Wt, int tid) {
  #pragma unroll
  for (int it = 0; it < 4; ++it) {
    int qq = tid + it * 512;            // 16B chunk id, 0..2047
    int r = qq >> 5, pb = qq & 31;
    uint4 v = *(const uint4*)((const char*)Wt + (size_t)qq * 16);
    *(uint4*)(dstb + r * 512 + ((pb ^ (r & 7)) << 4)) = v;
  }
}

// =====================================================================
// K2: FUSED per-(b,t), 64 KB LDS, 512 thr (8 waves), grid 512,
// 2 blocks/CU. Order: V-proj (3-term), K-proj (2-term), attention
// (S 2-term, PV 1-term). 5 barriers; after the last one LDS is
// read-only (in-register P redistribution) -> race-free.
// R9: every phase's loads pre-issued during the previous phase's tail
// (cross-barrier reg preload), in-phase prefetch depth 4.
// =====================================================================
__global__ __launch_bounds__(512, 4) void k_fused(
    const float* __restrict__ Xm, const float* __restrict__ Ym,
    const unsigned short* __restrict__ Wkth,
    const unsigned short* __restrict__ Wvth, const unsigned short* __restrict__ Wvtl,
    const float* __restrict__ bk, const float* __restrict__ bv,
    const unsigned short* __restrict__ Qh, const unsigned short* __restrict__ Ql,
    unsigned short* __restrict__ R,      // [bt][256 i][64 vd] bf16
    float* __restrict__ Sc) {            // [bt][256 i] raw row max
  __shared__ __align__(16) char smemb[65536];   // 64 KB
  int tid = threadIdx.x;
  int bt = blockIdx.x, b = bt >> 6;
  int w = tid >> 6, lane = tid & 63, c = lane & 15, g = lane >> 4;

  const float* yr0 = Ym + (size_t)bt * 65536 + (size_t)(w * 32 + c) * 256 + g * 8;
  const float* yr1 = yr0 + 16 * 256;
  const float* xr0 = Xm + (size_t)bt * 65536 + (size_t)(w * 32 + c) * 256 + g * 8;
  const float* xr1 = xr0 + 16 * 256;

  // ---- pre-issue V-phase chunks 0..3 (fly during Wv staging) ----
  float4 pby[4][4];
  #pragma unroll
  for (int s = 0; s < 4; ++s) {
    pby[s][0] = *(const float4*)(yr0 + s * 32);
    pby[s][1] = *(const float4*)(yr0 + s * 32 + 4);
    pby[s][2] = *(const float4*)(yr1 + s * 32);
    pby[s][3] = *(const float4*)(yr1 + s * 32 + 4);
  }
  // ---- stage Wv hi -> R1, Wv lo -> R2 ----
  stage_plane(smemb, Wvth, tid);
  stage_plane(smemb + R2B, Wvtl, tid);
  __syncthreads();                                   // barrier 1

  // ---------------- Phase B: V-proj (normal: M=j, N=vd), 3-term --------
  f32x4 vacc[2][4];
  #pragma unroll
  for (int mf = 0; mf < 2; ++mf)
    #pragma unroll
    for (int nf = 0; nf < 4; ++nf) vacc[mf][nf] = (f32x4)0.f;
  #pragma unroll
  for (int ks = 0; ks < 8; ++ks) {
    int s = ks & 3;
    float y0[8], y1[8];
    *(float4*)&y0[0] = pby[s][0]; *(float4*)&y0[4] = pby[s][1];
    *(float4*)&y1[0] = pby[s][2]; *(float4*)&y1[4] = pby[s][3];
    if (ks < 4) {   // reload slot with chunk ks+4
      pby[s][0] = *(const float4*)(yr0 + (ks + 4) * 32);
      pby[s][1] = *(const float4*)(yr0 + (ks + 4) * 32 + 4);
      pby[s][2] = *(const float4*)(yr1 + (ks + 4) * 32);
      pby[s][3] = *(const float4*)(yr1 + (ks + 4) * 32 + 4);
    }
    bf16x8 a0h, a0l, a1h, a1l;
    split8(y0, a0h, a0l);
    split8(y1, a1h, a1l);
    #pragma unroll
    for (int nf = 0; nf < 4; ++nf) {
      int r = nf * 16 + c;
      int ba = r * 512 + (((ks * 4 + g) ^ (r & 7)) << 4);
      bf16x8 bwh = *(const bf16x8*)(smemb + ba);
      bf16x8 bwl = *(const bf16x8*)(smemb + R2B + ba);
      vacc[0][nf] = MFMA16(a0h, bwh, vacc[0][nf]);
      vacc[0][nf] = MFMA16(a0l, bwh, vacc[0][nf]);
      vacc[0][nf] = MFMA16(a0h, bwl, vacc[0][nf]);
      vacc[1][nf] = MFMA16(a1h, bwh, vacc[1][nf]);
      vacc[1][nf] = MFMA16(a1l, bwh, vacc[1][nf]);
      vacc[1][nf] = MFMA16(a1h, bwl, vacc[1][nf]);
    }
  }
  __syncthreads();                                   // barrier 2 (Wv reads done)

  // ---- pre-issue K-phase chunks 0..3 (fly during epilogue + Wk stage) ----
  float4 pbx[4][4];
  #pragma unroll
  for (int s = 0; s < 4; ++s) {
    pbx[s][0] = *(const float4*)(xr0 + s * 32);
    pbx[s][1] = *(const float4*)(xr0 + s * 32 + 4);
    pbx[s][2] = *(const float4*)(xr1 + s * 32);
    pbx[s][3] = *(const float4*)(xr1 + s * 32 + 4);
  }
  // ---- epilogue V: write V-hi -> R2 (over Wv-lo); stage Wk-hi -> R1 ----
  #pragma unroll
  for (int nf = 0; nf < 4; ++nf) {
    int vd = nf * 16 + c;
    float bs = bv[vd];
    #pragma unroll
    for (int mf = 0; mf < 2; ++mf) {   // element (j = w*32+mf*16+4g+r, vd)
      bf16x4 ph;
      #pragma unroll
      for (int r = 0; r < 4; ++r) ph[r] = (short)f2bf(vacc[mf][nf][r] + bs);
      int pb = w * 4 + mf * 2 + (g >> 1);
      int ba = R2B + vd * 512 + ((pb ^ (vd & 7)) << 4) + (g & 1) * 8;
      *(bf16x4*)(smemb + ba) = ph;
    }
  }
  stage_plane(smemb, Wkth, tid);
  __syncthreads();                                   // barrier 3

  // ---------------- Phase A: K-proj (swapped: M=kd, N=j), 2-term --------
  f32x4 kacc[4][2];
  #pragma unroll
  for (int mf = 0; mf < 4; ++mf) { kacc[mf][0] = (f32x4)0.f; kacc[mf][1] = (f32x4)0.f; }
  #pragma unroll
  for (int ks = 0; ks < 8; ++ks) {
    int s = ks & 3;
    float x0[8], x1[8];
    *(float4*)&x0[0] = pbx[s][0]; *(float4*)&x0[4] = pbx[s][1];
    *(float4*)&x1[0] = pbx[s][2]; *(float4*)&x1[4] = pbx[s][3];
    if (ks < 4) {
      pbx[s][0] = *(const float4*)(xr0 + (ks + 4) * 32);
      pbx[s][1] = *(const float4*)(xr0 + (ks + 4) * 32 + 4);
      pbx[s][2] = *(const float4*)(xr1 + (ks + 4) * 32);
      pbx[s][3] = *(const float4*)(xr1 + (ks + 4) * 32 + 4);
    }
    bf16x8 b0h, b0l, b1h, b1l;
    split8(x0, b0h, b0l);
    split8(x1, b1h, b1l);
    #pragma unroll
    for (int mf = 0; mf < 4; ++mf) {
      int r = mf * 16 + c;
      int ba = r * 512 + (((ks * 4 + g) ^ (r & 7)) << 4);
      bf16x8 awh = *(const bf16x8*)(smemb + ba);
      kacc[mf][0] = MFMA16(awh, b0h, kacc[mf][0]);
      kacc[mf][0] = MFMA16(awh, b0l, kacc[mf][0]);
      kacc[mf][1] = MFMA16(awh, b1h, kacc[mf][1]);
      kacc[mf][1] = MFMA16(awh, b1l, kacc[mf][1]);
    }
  }
  __syncthreads();                                   // barrier 4 (Wk reads done)

  // ---- pre-issue Q frags for both ic (fly during K epilogue) ----
  bf16x8 qbh[2][2], qbl[2][2];   // [ks][ic]
  #pragma unroll
  for (int ks = 0; ks < 2; ++ks)
    #pragma unroll
    for (int ic = 0; ic < 2; ++ic) {
      size_t qo = ((size_t)b * NI + w * 32 + ic * 16 + c) * NKD + ks * 32 + g * 8;
      qbh[ks][ic] = *(const bf16x8*)(Qh + qo);
      qbl[ks][ic] = *(const bf16x8*)(Ql + qo);
    }
  // ---- epilogue K: write K-hi -> R1 (over Wk-hi) ----
  #pragma unroll
  for (int nf = 0; nf < 2; ++nf) {
    int j = w * 32 + nf * 16 + c;
    #pragma unroll
    for (int mf = 0; mf < 4; ++mf) {   // element (kd = mf*16+4g+r, j)
      bf16x4 ph;
      #pragma unroll
      for (int r = 0; r < 4; ++r)
        ph[r] = (short)f2bf(kacc[mf][nf][r] + bk[mf * 16 + g * 4 + r]);
      int pb = mf * 2 + (g >> 1);
      int ba = j * 128 + ((pb ^ (j & 7)) << 4) + (g & 1) * 8;
      *(bf16x4*)(smemb + ba) = ph;
    }
  }
  __syncthreads();                                   // barrier 5: LDS read-only now

  // ---------------- Phase C: attention (wave w: i = w*32 .. +32) --------
  #pragma unroll
  for (int ic = 0; ic < 2; ++ic) {
    int i = w * 32 + ic * 16 + c;

    // S^T = K * Q^T (2-term): sa[jf] holds S^T[j = 16jf+4g+r][i]
    f32x4 sa[16];
    #pragma unroll
    for (int jf = 0; jf < 16; ++jf) sa[jf] = (f32x4)0.f;
    #pragma unroll
    for (int jf = 0; jf < 16; ++jf) {
      int j = jf * 16 + c;
      #pragma unroll
      for (int ks = 0; ks < 2; ++ks) {
        int ba = j * 128 + (((ks * 4 + g) ^ (j & 7)) << 4);
        bf16x8 kh = *(const bf16x8*)(smemb + ba);
        sa[jf] = MFMA16(kh, qbh[ks][ic], sa[jf]);
        sa[jf] = MFMA16(kh, qbl[ks][ic], sa[jf]);
      }
    }

    // softmax over j (lane-local + 2 shfl)
    float mx = sa[0][0];
    #pragma unroll
    for (int jf = 0; jf < 16; ++jf)
      #pragma unroll
      for (int r = 0; r < 4; ++r) mx = fmaxf(mx, sa[jf][r]);
    mx = fmaxf(mx, __shfl_xor(mx, 16));
    mx = fmaxf(mx, __shfl_xor(mx, 32));
    if (g == 0) Sc[(size_t)bt * NI + i] = mx;   // raw max
    float sum = 0.f;
    #pragma unroll
    for (int jf = 0; jf < 16; ++jf)
      #pragma unroll
      for (int r = 0; r < 4; ++r) {
        float p = __expf((sa[jf][r] - mx) * SCL);
        sa[jf][r] = p;
        sum += p;
      }
    sum += __shfl_xor(sum, 16);
    sum += __shfl_xor(sum, 32);
    float linv = 1.0f / sum;

    // pack P into bf16-pair words: plo/phi[jf] = j {16jf+4g+0,1}/{2,3}
    unsigned int plo[16], phi[16];
    #pragma unroll
    for (int jf = 0; jf < 16; ++jf) {
      plo[jf] = (unsigned int)f2bf(sa[jf][0]) | ((unsigned int)f2bf(sa[jf][1]) << 16);
      phi[jf] = (unsigned int)f2bf(sa[jf][2]) | ((unsigned int)f2bf(sa[jf][3]) << 16);
    }

    // in-register P^T redistribution (verified R4/R6/R7/R8)
    int srcA = c + 32 * (g & 1);
    int srcB = srcA + 16;
    bool hiH = (g >= 2);

    f32x4 racc[4];
    #pragma unroll
    for (int vf = 0; vf < 4; ++vf) racc[vf] = (f32x4)0.f;
    #pragma unroll
    for (int js = 0; js < 8; ++js) {
      int a0 = __shfl((int)plo[2 * js], srcA);
      int a1 = __shfl((int)phi[2 * js], srcA);
      int a2 = __shfl((int)plo[2 * js], srcB);
      int a3 = __shfl((int)phi[2 * js], srcB);
      int b0 = __shfl((int)plo[2 * js + 1], srcA);
      int b1 = __shfl((int)phi[2 * js + 1], srcA);
      int b2 = __shfl((int)plo[2 * js + 1], srcB);
      int b3 = __shfl((int)phi[2 * js + 1], srcB);
      uint32x4 pw;
      pw[0] = (unsigned int)(hiH ? b0 : a0);
      pw[1] = (unsigned int)(hiH ? b1 : a1);
      pw[2] = (unsigned int)(hiH ? b2 : a2);
      pw[3] = (unsigned int)(hiH ? b3 : a3);
      bf16x8 pf = __builtin_bit_cast(bf16x8, pw);
      #pragma unroll
      for (int vf = 0; vf < 4; ++vf) {
        int vd = vf * 16 + c;
        int vba = R2B + vd * 512 + (((js * 4 + g) ^ (vd & 7)) << 4);
        bf16x8 vh = *(const bf16x8*)(smemb + vba);
        racc[vf] = MFMA16(vh, pf, racc[vf]);
      }
    }

    // write R[bt][i][vd] bf16, normalized; element (vd = vf*16+4g+r, i)
    #pragma unroll
    for (int vf = 0; vf < 4; ++vf) {
      bf16x4 rk;
      #pragma unroll
      for (int r = 0; r < 4; ++r) rk[r] = (short)f2bf(racc[vf][r] * linv);
      *(bf16x4*)(R + ((size_t)bt * NI + i) * NKD + vf * 16 + g * 4) = rk;
    }
  }
}

// =====================================================================
// K3: level-2 attention over t. 256 thr (4 waves), grid 512.
// Wave handles one (b,i); lane = t for softmax, vd for output.
// =====================================================================
__global__ __launch_bounds__(256) void k_level2(
    const float* __restrict__ Sc,         // [bt][256]
    const unsigned short* __restrict__ R, // [bt][256][64] bf16
    float* __restrict__ out) {            // [b][256][64] f32
  int w = threadIdx.x >> 6, lane = threadIdx.x & 63;
  int bi = blockIdx.x * 4 + w;
  int b = bi >> 8, i = bi & 255;
  float sc = Sc[((size_t)b * NT + lane) * NI + i];
  float mx = sc;
  #pragma unroll
  for (int off = 32; off; off >>= 1) mx = fmaxf(mx, __shfl_xor(mx, off));
  float e = __expf((sc - mx) * SCL);
  float sum = e;
  #pragma unroll
  for (int off = 32; off; off >>= 1) sum += __shfl_xor(sum, off);
  float wn = e / sum;
  float acc = 0.f;
  for (int t = 0; t < NT; ++t) {
    float wt = __shfl(wn, t);
    acc = fmaf(wt, bf2f(R[(((size_t)b * NT + t) * NI + i) * NKD + lane]), acc);
  }
  out[((size_t)b * NI + i) * NVD + lane] = acc;
}

// =====================================================================
extern "C" void kernel_launch(void* const* d_in, const int* in_sizes, int n_in,
                              void* d_out, int out_size, void* d_ws, size_t ws_size,
                              hipStream_t stream) {
  const float* x   = (const float*)d_in[0];
  const float* mxp = (const float*)d_in[1];
  const float* myp = (const float*)d_in[2];
  const float* Wq  = (const float*)d_in[3];
  const float* bq  = (const float*)d_in[4];
  const float* Wk  = (const float*)d_in[5];
  const float* bk  = (const float*)d_in[6];
  const float* Wv  = (const float*)d_in[7];
  const float* bv  = (const float*)d_in[8];
  float* out = (float*)d_out;

  // workspace carve (~18 MB)
  char* p = (char*)d_ws;
  auto alloc = [&](size_t bytes) { char* r = p; p += (bytes + 255) & ~(size_t)255; return r; };
  unsigned short* Qh   = (unsigned short*)alloc(2048 * 64 * 2);
  unsigned short* Ql   = (unsigned short*)alloc(2048 * 64 * 2);
  unsigned short* Rw   = (unsigned short*)alloc((size_t)131072 * 64 * 2);
  float*          Scw  = (float*)alloc((size_t)131072 * 4);
  unsigned short* Wkth = (unsigned short*)alloc(64 * 256 * 2);
  unsigned short* Wvth = (unsigned short*)alloc(64 * 256 * 2);
  unsigned short* Wvtl = (unsigned short*)alloc(64 * 256 * 2);

  hipLaunchKernelGGL(k_prep_projq, dim3(256 + NB * NI), dim3(64), 0, stream,
                     x, Wq, bq, Wk, Wv, Wkth, Wvth, Wvtl, Qh, Ql);
  hipLaunchKernelGGL(k_fused, dim3(NB * NT), dim3(512), 0, stream,
                     mxp, myp, Wkth, Wvth, Wvtl, bk, bv, Qh, Ql, Rw, Scw);
  hipLaunchKernelGGL(k_level2, dim3(512), dim3(256), 0, stream, Scw, Rw, out);
}